// Round 1
// baseline (1286.215 us; speedup 1.0000x reference)
//
#include <hip/hip_runtime.h>
#include <math.h>

#define NN 50000
#define EE 800000
#define AIN 256
#define OH 128
#define HH 4
#define DD 32

static __device__ __forceinline__ float4 f4zero() { float4 r; r.x=r.y=r.z=r.w=0.f; return r; }

// ---------------------------------------------------------------------------
// Generic GEMM: Y[M x 128] = X[M x K] @ W[K x 128] + bias, fp32, LDS-tiled.
// Block: 256 threads -> 32 rows x 128 cols. K % 32 == 0.
// ---------------------------------------------------------------------------
__global__ __launch_bounds__(256) void gemm_bias_k(
    const float* __restrict__ X, const float* __restrict__ W,
    const float* __restrict__ bias, float* __restrict__ Y,
    int M, int K)
{
    __shared__ float xs[32][32];    // xs[k][r]
    __shared__ float ws[32][128];   // ws[k][c]
    const int tid  = threadIdx.x;
    const int row0 = blockIdx.x * 32;
    const int c0   = (tid & 31) * 4;
    const int r0   = (tid >> 5) * 4;
    const int lr   = tid >> 3;          // 0..31 row for X load
    const int lk   = (tid & 7) * 4;     // k0 for X load
    const int wr   = tid >> 5;          // 0..7 base k for W load

    float acc[4][4];
    #pragma unroll
    for (int i = 0; i < 4; ++i)
        #pragma unroll
        for (int j = 0; j < 4; ++j) acc[i][j] = 0.f;

    for (int kt = 0; kt < K; kt += 32) {
        float4 xv = f4zero();
        const int grow = row0 + lr;
        if (grow < M) xv = *(const float4*)&X[(size_t)grow * K + kt + lk];
        xs[lk + 0][lr] = xv.x; xs[lk + 1][lr] = xv.y;
        xs[lk + 2][lr] = xv.z; xs[lk + 3][lr] = xv.w;
        #pragma unroll
        for (int j = 0; j < 4; ++j) {
            const int k = wr + 8 * j;
            *(float4*)&ws[k][c0] = *(const float4*)&W[(size_t)(kt + k) * OH + c0];
        }
        __syncthreads();
        #pragma unroll
        for (int k = 0; k < 32; ++k) {
            const float4 a = *(const float4*)&xs[k][r0];
            const float4 b = *(const float4*)&ws[k][c0];
            acc[0][0] += a.x*b.x; acc[0][1] += a.x*b.y; acc[0][2] += a.x*b.z; acc[0][3] += a.x*b.w;
            acc[1][0] += a.y*b.x; acc[1][1] += a.y*b.y; acc[1][2] += a.y*b.z; acc[1][3] += a.y*b.w;
            acc[2][0] += a.z*b.x; acc[2][1] += a.z*b.y; acc[2][2] += a.z*b.z; acc[2][3] += a.z*b.w;
            acc[3][0] += a.w*b.x; acc[3][1] += a.w*b.y; acc[3][2] += a.w*b.z; acc[3][3] += a.w*b.w;
        }
        __syncthreads();
    }

    const float4 bv = *(const float4*)&bias[c0];
    #pragma unroll
    for (int i = 0; i < 4; ++i) {
        const int row = row0 + r0 + i;
        if (row < M) {
            float4 o;
            o.x = acc[i][0] + bv.x; o.y = acc[i][1] + bv.y;
            o.z = acc[i][2] + bv.z; o.w = acc[i][3] + bv.w;
            *(float4*)&Y[(size_t)row * OH + c0] = o;
        }
    }
}

// ---------------------------------------------------------------------------
// Edge scatter: one 64-lane wave per edge. 128 elems = lane and lane+64.
// Heads: elem/32. Scores reduced via shfl_xor over 32-lane groups.
// ---------------------------------------------------------------------------
__global__ __launch_bounds__(256) void edge_k(
    const float* __restrict__ q99, const float* __restrict__ k99,
    const float* __restrict__ v99, const int* __restrict__ src,
    const int* __restrict__ dst, const float* __restrict__ feat,
    float* __restrict__ wv, float* __restrict__ z, int Ecount)
{
    const int e = blockIdx.x * 4 + (threadIdx.x >> 6);
    if (e >= Ecount) return;
    const int lane = threadIdx.x & 63;
    const int s = src[e];
    const int d = dst[e];
    const float f = feat[(size_t)e * 2];

    const float* krow = k99 + (size_t)s * OH;
    const float* qrow = q99 + (size_t)d * OH;
    const float* vrow = v99 + (size_t)s * OH;

    float p0 = krow[lane]      * qrow[lane];
    float p1 = krow[lane + 64] * qrow[lane + 64];
    #pragma unroll
    for (int m = 16; m >= 1; m >>= 1) {
        p0 += __shfl_xor(p0, m, 32);
        p1 += __shfl_xor(p1, m, 32);
    }
    const float SCALE = 0.088388347648318447f;  // 1/sqrt(128)
    float s0 = p0 * f * SCALE; s0 = fminf(5.f, fmaxf(-5.f, s0)); s0 = expf(s0);
    float s1 = p1 * f * SCALE; s1 = fminf(5.f, fmaxf(-5.f, s1)); s1 = expf(s1);

    atomicAdd(&wv[(size_t)d * OH + lane],      vrow[lane]      * s0);
    atomicAdd(&wv[(size_t)d * OH + lane + 64], vrow[lane + 64] * s1);
    if ((lane & 31) == 0) {
        atomicAdd(&z[(size_t)d * HH +     (lane >> 5)], s0);
        atomicAdd(&z[(size_t)d * HH + 2 + (lane >> 5)], s1);
    }
}

// ---------------------------------------------------------------------------
// Output GEMM with fused attention-normalize (A = wv/(z+1)) and LN epilogue:
// ao = att @ Wo + bo ; ah = ffn + ao ; out = ah + LN(ah)*g + b
// Block: 256 threads -> 32 rows x 128 cols, K = 128.
// ---------------------------------------------------------------------------
__global__ __launch_bounds__(256) void attn_out_k(
    const float* __restrict__ wv, const float* __restrict__ z,
    const float* __restrict__ Wo, const float* __restrict__ bo,
    const float* __restrict__ ffn, const float* __restrict__ g,
    const float* __restrict__ bln, float* __restrict__ Y, int M)
{
    __shared__ float xs[32][32];
    __shared__ float ws[32][128];
    const int tid  = threadIdx.x;
    const int row0 = blockIdx.x * 32;
    const int c0   = (tid & 31) * 4;
    const int r0   = (tid >> 5) * 4;
    const int lr   = tid >> 3;
    const int lk   = (tid & 7) * 4;
    const int wr   = tid >> 5;

    float acc[4][4];
    #pragma unroll
    for (int i = 0; i < 4; ++i)
        #pragma unroll
        for (int j = 0; j < 4; ++j) acc[i][j] = 0.f;

    for (int kt = 0; kt < OH; kt += 32) {
        float4 xv = f4zero();
        const int grow = row0 + lr;
        if (grow < M) {
            xv = *(const float4*)&wv[(size_t)grow * OH + kt + lk];
            const float zz = 1.f / (z[(size_t)grow * HH + (kt >> 5)] + 1.0f);
            xv.x *= zz; xv.y *= zz; xv.z *= zz; xv.w *= zz;
        }
        xs[lk + 0][lr] = xv.x; xs[lk + 1][lr] = xv.y;
        xs[lk + 2][lr] = xv.z; xs[lk + 3][lr] = xv.w;
        #pragma unroll
        for (int j = 0; j < 4; ++j) {
            const int k = wr + 8 * j;
            *(float4*)&ws[k][c0] = *(const float4*)&Wo[(size_t)(kt + k) * OH + c0];
        }
        __syncthreads();
        #pragma unroll
        for (int k = 0; k < 32; ++k) {
            const float4 a = *(const float4*)&xs[k][r0];
            const float4 b = *(const float4*)&ws[k][c0];
            acc[0][0] += a.x*b.x; acc[0][1] += a.x*b.y; acc[0][2] += a.x*b.z; acc[0][3] += a.x*b.w;
            acc[1][0] += a.y*b.x; acc[1][1] += a.y*b.y; acc[1][2] += a.y*b.z; acc[1][3] += a.y*b.w;
            acc[2][0] += a.z*b.x; acc[2][1] += a.z*b.y; acc[2][2] += a.z*b.z; acc[2][3] += a.z*b.w;
            acc[3][0] += a.w*b.x; acc[3][1] += a.w*b.y; acc[3][2] += a.w*b.z; acc[3][3] += a.w*b.w;
        }
        __syncthreads();
    }

    const float4 bv = *(const float4*)&bo[c0];
    const float4 gv = *(const float4*)&g[c0];
    const float4 lv = *(const float4*)&bln[c0];

    #pragma unroll
    for (int i = 0; i < 4; ++i) {
        const int row = row0 + r0 + i;
        float4 f4 = f4zero();
        if (row < M) f4 = *(const float4*)&ffn[(size_t)row * OH + c0];
        float ah0 = acc[i][0] + bv.x + f4.x;
        float ah1 = acc[i][1] + bv.y + f4.y;
        float ah2 = acc[i][2] + bv.z + f4.z;
        float ah3 = acc[i][3] + bv.w + f4.w;
        // row mean over 128 cols (32 lanes x 4 cols)
        float sum = ah0 + ah1 + ah2 + ah3;
        #pragma unroll
        for (int m = 16; m >= 1; m >>= 1) sum += __shfl_xor(sum, m, 32);
        const float mean = sum * (1.f / 128.f);
        const float d0 = ah0 - mean, d1 = ah1 - mean, d2 = ah2 - mean, d3 = ah3 - mean;
        float vs = d0*d0 + d1*d1 + d2*d2 + d3*d3;
        #pragma unroll
        for (int m = 16; m >= 1; m >>= 1) vs += __shfl_xor(vs, m, 32);
        const float inv = rsqrtf(vs * (1.f / 128.f) + 1e-5f);
        if (row < M) {
            float4 o;
            o.x = ah0 + d0 * inv * gv.x + lv.x;
            o.y = ah1 + d1 * inv * gv.y + lv.y;
            o.z = ah2 + d2 * inv * gv.z + lv.z;
            o.w = ah3 + d3 * inv * gv.w + lv.w;
            *(float4*)&Y[(size_t)row * OH + c0] = o;
        }
    }
}

// ---------------------------------------------------------------------------
extern "C" void kernel_launch(void* const* d_in, const int* in_sizes, int n_in,
                              void* d_out, int out_size, void* d_ws, size_t ws_size,
                              hipStream_t stream) {
    const float* x99   = (const float*)d_in[2];
    const float* feat0 = (const float*)d_in[3];
    const float* feat1 = (const float*)d_in[4];
    const float* Waq   = (const float*)d_in[10];
    const float* Wak   = (const float*)d_in[11];
    const float* Wav   = (const float*)d_in[12];
    const float* Wao   = (const float*)d_in[13];
    const float* Waffn = (const float*)d_in[14];
    const float* baq   = (const float*)d_in[20];
    const float* bak   = (const float*)d_in[21];
    const float* bav   = (const float*)d_in[22];
    const float* bao   = (const float*)d_in[23];
    const float* baffn = (const float*)d_in[24];
    const float* aln_b = (const float*)d_in[26];
    const float* aln_g = (const float*)d_in[28];
    const int* src0 = (const int*)d_in[29];
    const int* dst0 = (const int*)d_in[30];
    const int* src1 = (const int*)d_in[31];
    const int* dst1 = (const int*)d_in[32];

    float* q99 = (float*)d_ws;
    float* k99 = q99 + (size_t)NN * OH;
    float* v99 = k99 + (size_t)NN * OH;
    float* ffn = v99 + (size_t)NN * OH;
    float* wv  = ffn + (size_t)NN * OH;
    float* z   = wv  + (size_t)NN * OH;

    float* out = (float*)d_out;

    const int gemm_grid = (NN + 31) / 32;
    gemm_bias_k<<<gemm_grid, 256, 0, stream>>>(x99, Waq,   baq,   q99, NN, AIN);
    gemm_bias_k<<<gemm_grid, 256, 0, stream>>>(x99, Wak,   bak,   k99, NN, AIN);
    gemm_bias_k<<<gemm_grid, 256, 0, stream>>>(x99, Wav,   bav,   v99, NN, AIN);
    gemm_bias_k<<<gemm_grid, 256, 0, stream>>>(x99, Waffn, baffn, ffn, NN, AIN);

    const int edge_grid = (EE + 3) / 4;

    // edge set 0
    hipMemsetAsync(wv, 0, (size_t)NN * OH * sizeof(float), stream);
    hipMemsetAsync(z,  0, (size_t)NN * HH * sizeof(float), stream);
    edge_k<<<edge_grid, 256, 0, stream>>>(q99, k99, v99, src0, dst0, feat0, wv, z, EE);
    attn_out_k<<<gemm_grid, 256, 0, stream>>>(wv, z, Wao, bao, ffn, aln_g, aln_b, out, NN);

    // edge set 1
    hipMemsetAsync(wv, 0, (size_t)NN * OH * sizeof(float), stream);
    hipMemsetAsync(z,  0, (size_t)NN * HH * sizeof(float), stream);
    edge_k<<<edge_grid, 256, 0, stream>>>(q99, k99, v99, src1, dst1, feat1, wv, z, EE);
    attn_out_k<<<gemm_grid, 256, 0, stream>>>(wv, z, Wao, bao, ffn, aln_g, aln_b, out + (size_t)NN * OH, NN);
}

// Round 2
// 1183.842 us; speedup vs baseline: 1.0865x; 1.0865x over previous
//
#include <hip/hip_runtime.h>
#include <math.h>

#define NN 50000
#define EE 800000
#define AIN 256
#define OH 128
#define HH 4
#define DD 32

static __device__ __forceinline__ float4 f4zero() { float4 r; r.x=r.y=r.z=r.w=0.f; return r; }

// ---------------------------------------------------------------------------
// Generic GEMM: Y[M x 128] = X[M x K] @ W[K x 128] + bias, fp32, LDS-tiled.
// Block: 256 threads -> 32 rows x 128 cols. K % 32 == 0.
// ---------------------------------------------------------------------------
__global__ __launch_bounds__(256) void gemm_bias_k(
    const float* __restrict__ X, const float* __restrict__ W,
    const float* __restrict__ bias, float* __restrict__ Y,
    int M, int K)
{
    __shared__ float xs[32][32];    // xs[k][r]
    __shared__ float ws[32][128];   // ws[k][c]
    const int tid  = threadIdx.x;
    const int row0 = blockIdx.x * 32;
    const int c0   = (tid & 31) * 4;
    const int r0   = (tid >> 5) * 4;
    const int lr   = tid >> 3;          // 0..31 row for X load
    const int lk   = (tid & 7) * 4;     // k0 for X load
    const int wr   = tid >> 5;          // 0..7 base k for W load

    float acc[4][4];
    #pragma unroll
    for (int i = 0; i < 4; ++i)
        #pragma unroll
        for (int j = 0; j < 4; ++j) acc[i][j] = 0.f;

    for (int kt = 0; kt < K; kt += 32) {
        float4 xv = f4zero();
        const int grow = row0 + lr;
        if (grow < M) xv = *(const float4*)&X[(size_t)grow * K + kt + lk];
        xs[lk + 0][lr] = xv.x; xs[lk + 1][lr] = xv.y;
        xs[lk + 2][lr] = xv.z; xs[lk + 3][lr] = xv.w;
        #pragma unroll
        for (int j = 0; j < 4; ++j) {
            const int k = wr + 8 * j;
            *(float4*)&ws[k][c0] = *(const float4*)&W[(size_t)(kt + k) * OH + c0];
        }
        __syncthreads();
        #pragma unroll
        for (int k = 0; k < 32; ++k) {
            const float4 a = *(const float4*)&xs[k][r0];
            const float4 b = *(const float4*)&ws[k][c0];
            acc[0][0] += a.x*b.x; acc[0][1] += a.x*b.y; acc[0][2] += a.x*b.z; acc[0][3] += a.x*b.w;
            acc[1][0] += a.y*b.x; acc[1][1] += a.y*b.y; acc[1][2] += a.y*b.z; acc[1][3] += a.y*b.w;
            acc[2][0] += a.z*b.x; acc[2][1] += a.z*b.y; acc[2][2] += a.z*b.z; acc[2][3] += a.z*b.w;
            acc[3][0] += a.w*b.x; acc[3][1] += a.w*b.y; acc[3][2] += a.w*b.z; acc[3][3] += a.w*b.w;
        }
        __syncthreads();
    }

    const float4 bv = *(const float4*)&bias[c0];
    #pragma unroll
    for (int i = 0; i < 4; ++i) {
        const int row = row0 + r0 + i;
        if (row < M) {
            float4 o;
            o.x = acc[i][0] + bv.x; o.y = acc[i][1] + bv.y;
            o.z = acc[i][2] + bv.z; o.w = acc[i][3] + bv.w;
            *(float4*)&Y[(size_t)row * OH + c0] = o;
        }
    }
}

// ---------------------------------------------------------------------------
// CSR build: histogram over combined (set0, set1) dst, scan, scatter.
// cnt/off are length 2*NN (set1 nodes at offset NN).
// ---------------------------------------------------------------------------
__global__ __launch_bounds__(256) void hist_k(
    const int* __restrict__ dst0, const int* __restrict__ dst1, int* __restrict__ cnt)
{
    const int i = blockIdx.x * 256 + threadIdx.x;
    if (i >= 2 * EE) return;
    const int d = (i < EE) ? dst0[i] : (NN + dst1[i - EE]);
    atomicAdd(&cnt[d], 1);
}

// One block, 1024 threads. Exclusive scan of cnt[0..2*NN) into off; zeroes cnt
// (cnt is then reused as the scatter cursor, and ends back at full degree).
__global__ __launch_bounds__(1024) void scan_k(int* __restrict__ cnt, int* __restrict__ off)
{
    __shared__ int part[1024];
    const int NTOT = 2 * NN;
    const int SPAN = (NTOT + 1023) / 1024;   // 98
    const int t = threadIdx.x;
    const int base = t * SPAN;
    int local = 0;
    for (int i = 0; i < SPAN; ++i) {
        const int idx = base + i;
        if (idx < NTOT) local += cnt[idx];
    }
    part[t] = local;
    __syncthreads();
    // Hillis-Steele inclusive scan
    for (int st = 1; st < 1024; st <<= 1) {
        int v = (t >= st) ? part[t - st] : 0;
        __syncthreads();
        part[t] += v;
        __syncthreads();
    }
    int carry = (t == 0) ? 0 : part[t - 1];
    for (int i = 0; i < SPAN; ++i) {
        const int idx = base + i;
        if (idx < NTOT) {
            const int c = cnt[idx];
            off[idx] = carry;
            carry += c;
            cnt[idx] = 0;
        }
    }
}

__global__ __launch_bounds__(256) void scatter_k(
    const int* __restrict__ dst0, const int* __restrict__ dst1,
    const int* __restrict__ off, int* __restrict__ cnt, int* __restrict__ eidx)
{
    const int i = blockIdx.x * 256 + threadIdx.x;
    if (i >= 2 * EE) return;
    const int e = (i < EE) ? i : (i - EE);
    const int d = (i < EE) ? dst0[e] : (NN + dst1[e]);
    const int pos = off[d] + atomicAdd(&cnt[d], 1);
    eidx[pos] = e;
}

// ---------------------------------------------------------------------------
// Per-destination aggregation: one 64-lane wave per dst node. No atomics.
// Writes att = wv / (z+1) directly.
// ---------------------------------------------------------------------------
__global__ __launch_bounds__(256) void aggregate_k(
    const float* __restrict__ q99, const float* __restrict__ k99,
    const float* __restrict__ v99, const int* __restrict__ src,
    const float* __restrict__ feat, const int* __restrict__ eidx,
    const int* __restrict__ off, const int* __restrict__ deg,
    int nodeBase, float* __restrict__ att)
{
    const int n = blockIdx.x * 4 + (threadIdx.x >> 6);
    if (n >= NN) return;
    const int lane = threadIdx.x & 63;
    const int start = off[nodeBase + n];
    const int count = deg[nodeBase + n];

    const float q0 = q99[(size_t)n * OH + lane];
    const float q1 = q99[(size_t)n * OH + lane + 64];

    float acc0 = 0.f, acc1 = 0.f, z0 = 0.f, z1 = 0.f;
    const float SCALE = 0.088388347648318447f;  // 1/sqrt(128)

    for (int j = 0; j < count; ++j) {
        const int e = eidx[start + j];
        const int s = src[e];
        const float f = feat[(size_t)e * 2];
        const float* krow = k99 + (size_t)s * OH;
        const float* vrow = v99 + (size_t)s * OH;
        const float k0 = krow[lane], k1 = krow[lane + 64];
        const float v0 = vrow[lane], v1 = vrow[lane + 64];
        float p0 = k0 * q0, p1 = k1 * q1;
        #pragma unroll
        for (int m = 16; m >= 1; m >>= 1) {
            p0 += __shfl_xor(p0, m, 32);
            p1 += __shfl_xor(p1, m, 32);
        }
        float s0 = p0 * f * SCALE; s0 = fminf(5.f, fmaxf(-5.f, s0)); s0 = __expf(s0);
        float s1 = p1 * f * SCALE; s1 = fminf(5.f, fmaxf(-5.f, s1)); s1 = __expf(s1);
        acc0 = fmaf(v0, s0, acc0);
        acc1 = fmaf(v1, s1, acc1);
        z0 += s0;
        z1 += s1;
    }
    att[(size_t)n * OH + lane]      = acc0 / (z0 + 1.f);
    att[(size_t)n * OH + lane + 64] = acc1 / (z1 + 1.f);
}

// ---------------------------------------------------------------------------
// Output GEMM (att already normalized) with fused LN epilogue:
// ao = att @ Wo + bo ; ah = ffn + ao ; out = ah + LN(ah)*g + b
// ---------------------------------------------------------------------------
__global__ __launch_bounds__(256) void attn_out_k(
    const float* __restrict__ att,
    const float* __restrict__ Wo, const float* __restrict__ bo,
    const float* __restrict__ ffn, const float* __restrict__ g,
    const float* __restrict__ bln, float* __restrict__ Y, int M)
{
    __shared__ float xs[32][32];
    __shared__ float ws[32][128];
    const int tid  = threadIdx.x;
    const int row0 = blockIdx.x * 32;
    const int c0   = (tid & 31) * 4;
    const int r0   = (tid >> 5) * 4;
    const int lr   = tid >> 3;
    const int lk   = (tid & 7) * 4;
    const int wr   = tid >> 5;

    float acc[4][4];
    #pragma unroll
    for (int i = 0; i < 4; ++i)
        #pragma unroll
        for (int j = 0; j < 4; ++j) acc[i][j] = 0.f;

    for (int kt = 0; kt < OH; kt += 32) {
        float4 xv = f4zero();
        const int grow = row0 + lr;
        if (grow < M) xv = *(const float4*)&att[(size_t)grow * OH + kt + lk];
        xs[lk + 0][lr] = xv.x; xs[lk + 1][lr] = xv.y;
        xs[lk + 2][lr] = xv.z; xs[lk + 3][lr] = xv.w;
        #pragma unroll
        for (int j = 0; j < 4; ++j) {
            const int k = wr + 8 * j;
            *(float4*)&ws[k][c0] = *(const float4*)&Wo[(size_t)(kt + k) * OH + c0];
        }
        __syncthreads();
        #pragma unroll
        for (int k = 0; k < 32; ++k) {
            const float4 a = *(const float4*)&xs[k][r0];
            const float4 b = *(const float4*)&ws[k][c0];
            acc[0][0] += a.x*b.x; acc[0][1] += a.x*b.y; acc[0][2] += a.x*b.z; acc[0][3] += a.x*b.w;
            acc[1][0] += a.y*b.x; acc[1][1] += a.y*b.y; acc[1][2] += a.y*b.z; acc[1][3] += a.y*b.w;
            acc[2][0] += a.z*b.x; acc[2][1] += a.z*b.y; acc[2][2] += a.z*b.z; acc[2][3] += a.z*b.w;
            acc[3][0] += a.w*b.x; acc[3][1] += a.w*b.y; acc[3][2] += a.w*b.z; acc[3][3] += a.w*b.w;
        }
        __syncthreads();
    }

    const float4 bv = *(const float4*)&bo[c0];
    const float4 gv = *(const float4*)&g[c0];
    const float4 lv = *(const float4*)&bln[c0];

    #pragma unroll
    for (int i = 0; i < 4; ++i) {
        const int row = row0 + r0 + i;
        float4 f4 = f4zero();
        if (row < M) f4 = *(const float4*)&ffn[(size_t)row * OH + c0];
        float ah0 = acc[i][0] + bv.x + f4.x;
        float ah1 = acc[i][1] + bv.y + f4.y;
        float ah2 = acc[i][2] + bv.z + f4.z;
        float ah3 = acc[i][3] + bv.w + f4.w;
        float sum = ah0 + ah1 + ah2 + ah3;
        #pragma unroll
        for (int m = 16; m >= 1; m >>= 1) sum += __shfl_xor(sum, m, 32);
        const float mean = sum * (1.f / 128.f);
        const float d0 = ah0 - mean, d1 = ah1 - mean, d2 = ah2 - mean, d3 = ah3 - mean;
        float vs = d0*d0 + d1*d1 + d2*d2 + d3*d3;
        #pragma unroll
        for (int m = 16; m >= 1; m >>= 1) vs += __shfl_xor(vs, m, 32);
        const float inv = rsqrtf(vs * (1.f / 128.f) + 1e-5f);
        if (row < M) {
            float4 o;
            o.x = ah0 + d0 * inv * gv.x + lv.x;
            o.y = ah1 + d1 * inv * gv.y + lv.y;
            o.z = ah2 + d2 * inv * gv.z + lv.z;
            o.w = ah3 + d3 * inv * gv.w + lv.w;
            *(float4*)&Y[(size_t)row * OH + c0] = o;
        }
    }
}

// ---------------------------------------------------------------------------
extern "C" void kernel_launch(void* const* d_in, const int* in_sizes, int n_in,
                              void* d_out, int out_size, void* d_ws, size_t ws_size,
                              hipStream_t stream) {
    const float* x99   = (const float*)d_in[2];
    const float* feat0 = (const float*)d_in[3];
    const float* feat1 = (const float*)d_in[4];
    const float* Waq   = (const float*)d_in[10];
    const float* Wak   = (const float*)d_in[11];
    const float* Wav   = (const float*)d_in[12];
    const float* Wao   = (const float*)d_in[13];
    const float* Waffn = (const float*)d_in[14];
    const float* baq   = (const float*)d_in[20];
    const float* bak   = (const float*)d_in[21];
    const float* bav   = (const float*)d_in[22];
    const float* bao   = (const float*)d_in[23];
    const float* baffn = (const float*)d_in[24];
    const float* aln_b = (const float*)d_in[26];
    const float* aln_g = (const float*)d_in[28];
    const int* src0 = (const int*)d_in[29];
    const int* dst0 = (const int*)d_in[30];
    const int* src1 = (const int*)d_in[31];
    const int* dst1 = (const int*)d_in[32];

    float* q99 = (float*)d_ws;
    float* k99 = q99 + (size_t)NN * OH;
    float* v99 = k99 + (size_t)NN * OH;
    float* ffn = v99 + (size_t)NN * OH;
    float* att = ffn + (size_t)NN * OH;
    int*   cnt = (int*)(att + (size_t)NN * OH);   // 2*NN
    int*   off = cnt + 2 * NN;                    // 2*NN

    float* out = (float*)d_out;
    // Park eidx (1.6M ints = 6.4 MB) in d_out's second half; it is consumed
    // before attn_out writes that region.
    int* eidx = (int*)(out + (size_t)NN * OH);

    const int gemm_grid = (NN + 31) / 32;
    gemm_bias_k<<<gemm_grid, 256, 0, stream>>>(x99, Waq,   baq,   q99, NN, AIN);
    gemm_bias_k<<<gemm_grid, 256, 0, stream>>>(x99, Wak,   bak,   k99, NN, AIN);
    gemm_bias_k<<<gemm_grid, 256, 0, stream>>>(x99, Wav,   bav,   v99, NN, AIN);
    gemm_bias_k<<<gemm_grid, 256, 0, stream>>>(x99, Waffn, baffn, ffn, NN, AIN);

    // CSR build (both edge sets at once)
    hipMemsetAsync(cnt, 0, 2 * NN * sizeof(int), stream);
    const int eg = (2 * EE + 255) / 256;
    hist_k<<<eg, 256, 0, stream>>>(dst0, dst1, cnt);
    scan_k<<<1, 1024, 0, stream>>>(cnt, off);
    scatter_k<<<eg, 256, 0, stream>>>(dst0, dst1, off, cnt, eidx);

    const int agg_grid = (NN + 3) / 4;

    // edge set 0
    aggregate_k<<<agg_grid, 256, 0, stream>>>(q99, k99, v99, src0, feat0, eidx, off, cnt, 0, att);
    attn_out_k<<<gemm_grid, 256, 0, stream>>>(att, Wao, bao, ffn, aln_g, aln_b, out, NN);

    // edge set 1
    aggregate_k<<<agg_grid, 256, 0, stream>>>(q99, k99, v99, src1, feat1, eidx, off, cnt, NN, att);
    attn_out_k<<<gemm_grid, 256, 0, stream>>>(att, Wao, bao, ffn, aln_g, aln_b, out + (size_t)NN * OH, NN);
}

// Round 3
// 935.336 us; speedup vs baseline: 1.3751x; 1.2657x over previous
//
#include <hip/hip_runtime.h>
#include <math.h>

#define NN 50000
#define EE 800000
#define AIN 256
#define OH 128
#define HH 4
#define DD 32

#define NTOT   (2 * NN)          // 100000 counters (set0 nodes, then set1 nodes)
#define NTOT4  (NTOT / 4)        // 25000 int4s
#define SCANB  ((NTOT4 + 255) / 256)   // 98 blocks

static __device__ __forceinline__ float4 f4zero() { float4 r; r.x=r.y=r.z=r.w=0.f; return r; }

// ---------------------------------------------------------------------------
// Generic GEMM: Y[M x 128] = X[M x K] @ W[K x 128] + bias, fp32, LDS-tiled.
// Block: 256 threads -> 32 rows x 128 cols. K % 32 == 0.
// ---------------------------------------------------------------------------
__global__ __launch_bounds__(256) void gemm_bias_k(
    const float* __restrict__ X, const float* __restrict__ W,
    const float* __restrict__ bias, float* __restrict__ Y,
    int M, int K)
{
    __shared__ float xs[32][32];    // xs[k][r]
    __shared__ float ws[32][128];   // ws[k][c]
    const int tid  = threadIdx.x;
    const int row0 = blockIdx.x * 32;
    const int c0   = (tid & 31) * 4;
    const int r0   = (tid >> 5) * 4;
    const int lr   = tid >> 3;          // 0..31 row for X load
    const int lk   = (tid & 7) * 4;     // k0 for X load
    const int wr   = tid >> 5;          // 0..7 base k for W load

    float acc[4][4];
    #pragma unroll
    for (int i = 0; i < 4; ++i)
        #pragma unroll
        for (int j = 0; j < 4; ++j) acc[i][j] = 0.f;

    for (int kt = 0; kt < K; kt += 32) {
        float4 xv = f4zero();
        const int grow = row0 + lr;
        if (grow < M) xv = *(const float4*)&X[(size_t)grow * K + kt + lk];
        xs[lk + 0][lr] = xv.x; xs[lk + 1][lr] = xv.y;
        xs[lk + 2][lr] = xv.z; xs[lk + 3][lr] = xv.w;
        #pragma unroll
        for (int j = 0; j < 4; ++j) {
            const int k = wr + 8 * j;
            *(float4*)&ws[k][c0] = *(const float4*)&W[(size_t)(kt + k) * OH + c0];
        }
        __syncthreads();
        #pragma unroll
        for (int k = 0; k < 32; ++k) {
            const float4 a = *(const float4*)&xs[k][r0];
            const float4 b = *(const float4*)&ws[k][c0];
            acc[0][0] += a.x*b.x; acc[0][1] += a.x*b.y; acc[0][2] += a.x*b.z; acc[0][3] += a.x*b.w;
            acc[1][0] += a.y*b.x; acc[1][1] += a.y*b.y; acc[1][2] += a.y*b.z; acc[1][3] += a.y*b.w;
            acc[2][0] += a.z*b.x; acc[2][1] += a.z*b.y; acc[2][2] += a.z*b.z; acc[2][3] += a.z*b.w;
            acc[3][0] += a.w*b.x; acc[3][1] += a.w*b.y; acc[3][2] += a.w*b.z; acc[3][3] += a.w*b.w;
        }
        __syncthreads();
    }

    const float4 bv = *(const float4*)&bias[c0];
    #pragma unroll
    for (int i = 0; i < 4; ++i) {
        const int row = row0 + r0 + i;
        if (row < M) {
            float4 o;
            o.x = acc[i][0] + bv.x; o.y = acc[i][1] + bv.y;
            o.z = acc[i][2] + bv.z; o.w = acc[i][3] + bv.w;
            *(float4*)&Y[(size_t)row * OH + c0] = o;
        }
    }
}

// ---------------------------------------------------------------------------
// CSR build: histogram, two-level scan, scatter.
// ---------------------------------------------------------------------------
__global__ __launch_bounds__(256) void hist_k(
    const int* __restrict__ dst0, const int* __restrict__ dst1, int* __restrict__ cnt)
{
    const int i = blockIdx.x * 256 + threadIdx.x;
    if (i >= 2 * EE) return;
    const int d = (i < EE) ? dst0[i] : (NN + dst1[i - EE]);
    atomicAdd(&cnt[d], 1);
}

// Phase 1: per-block sums of 1024 counters (256 threads x int4).
__global__ __launch_bounds__(256) void scan1_k(const int* __restrict__ cnt, int* __restrict__ bsum)
{
    __shared__ int part[256];
    const int t = threadIdx.x;
    const int i4 = blockIdx.x * 256 + t;
    int s = 0;
    if (i4 < NTOT4) {
        const int4 c = ((const int4*)cnt)[i4];
        s = c.x + c.y + c.z + c.w;
    }
    part[t] = s;
    __syncthreads();
    #pragma unroll
    for (int st = 128; st >= 1; st >>= 1) {
        if (t < st) part[t] += part[t + st];
        __syncthreads();
    }
    if (t == 0) bsum[blockIdx.x] = part[0];
}

// Phase 2: one block scans the SCANB block sums (exclusive).
__global__ __launch_bounds__(128) void scan2_k(int* __restrict__ bsum)
{
    __shared__ int part[128];
    const int t = threadIdx.x;
    int v = (t < SCANB) ? bsum[t] : 0;
    part[t] = v;
    __syncthreads();
    for (int st = 1; st < 128; st <<= 1) {
        int u = (t >= st) ? part[t - st] : 0;
        __syncthreads();
        part[t] += u;
        __syncthreads();
    }
    if (t < SCANB) bsum[t] = part[t] - v;   // exclusive
}

// Phase 3: block-local exclusive scan + block offset -> off; zero cnt.
__global__ __launch_bounds__(256) void scan3_k(
    int* __restrict__ cnt, const int* __restrict__ bsum, int* __restrict__ off)
{
    __shared__ int part[256];
    const int t = threadIdx.x;
    const int i4 = blockIdx.x * 256 + t;
    int4 c = {0, 0, 0, 0};
    if (i4 < NTOT4) c = ((const int4*)cnt)[i4];
    const int s = c.x + c.y + c.z + c.w;
    part[t] = s;
    __syncthreads();
    for (int st = 1; st < 256; st <<= 1) {
        int u = (t >= st) ? part[t - st] : 0;
        __syncthreads();
        part[t] += u;
        __syncthreads();
    }
    if (i4 < NTOT4) {
        int base = bsum[blockIdx.x] + part[t] - s;
        int4 o;
        o.x = base;
        o.y = base + c.x;
        o.z = base + c.x + c.y;
        o.w = base + c.x + c.y + c.z;
        ((int4*)off)[i4] = o;
        ((int4*)cnt)[i4] = int4{0, 0, 0, 0};
    }
}

__global__ __launch_bounds__(256) void scatter_k(
    const int* __restrict__ dst0, const int* __restrict__ dst1,
    const int* __restrict__ off, int* __restrict__ cnt, int* __restrict__ eidx)
{
    const int i = blockIdx.x * 256 + threadIdx.x;
    if (i >= 2 * EE) return;
    const int e = (i < EE) ? i : (i - EE);
    const int d = (i < EE) ? dst0[e] : (NN + dst1[e]);
    const int pos = off[d] + atomicAdd(&cnt[d], 1);
    eidx[pos] = e;
}

// ---------------------------------------------------------------------------
// Per-destination aggregation: one 64-lane wave per dst node. No atomics.
// Lane l owns elements 2l, 2l+1 (same head: head = l/16). Score reduction is
// one 4-step shfl_xor over 16-lane groups. Writes att = wv/(z+1) directly.
// ---------------------------------------------------------------------------
__global__ __launch_bounds__(256) void aggregate_k(
    const float* __restrict__ q99, const float* __restrict__ k99,
    const float* __restrict__ v99, const int* __restrict__ src,
    const float* __restrict__ feat, const int* __restrict__ eidx,
    const int* __restrict__ off, const int* __restrict__ deg,
    int nodeBase, float* __restrict__ att)
{
    const int n = blockIdx.x * 4 + (threadIdx.x >> 6);
    if (n >= NN) return;
    const int lane = threadIdx.x & 63;
    const int start = off[nodeBase + n];
    const int count = deg[nodeBase + n];

    const float2 q2 = *(const float2*)&q99[(size_t)n * OH + 2 * lane];

    float accx = 0.f, accy = 0.f, z = 0.f;
    const float SCALE = 0.088388347648318447f;  // 1/sqrt(128)

    // 1-deep software pipeline on the eidx -> src/feat chase.
    int e0 = 0, s0 = 0; float f0 = 0.f;
    if (count > 0) {
        e0 = eidx[start];
        s0 = src[e0];
        f0 = feat[(size_t)e0 * 2];
    }
    for (int j = 0; j < count; ++j) {
        int s1 = 0; float f1 = 0.f;
        if (j + 1 < count) {
            const int e1 = eidx[start + j + 1];
            s1 = src[e1];
            f1 = feat[(size_t)e1 * 2];
        }
        const float2 k2 = *(const float2*)&k99[(size_t)s0 * OH + 2 * lane];
        const float2 v2 = *(const float2*)&v99[(size_t)s0 * OH + 2 * lane];
        float p = fmaf(k2.y, q2.y, k2.x * q2.x);
        #pragma unroll
        for (int m = 8; m >= 1; m >>= 1) p += __shfl_xor(p, m, 16);
        float sc = p * f0 * SCALE;
        sc = fminf(5.f, fmaxf(-5.f, sc));
        sc = __expf(sc);
        accx = fmaf(v2.x, sc, accx);
        accy = fmaf(v2.y, sc, accy);
        z += sc;
        s0 = s1; f0 = f1;
    }
    const float inv = 1.f / (z + 1.f);
    float2 o; o.x = accx * inv; o.y = accy * inv;
    *(float2*)&att[(size_t)n * OH + 2 * lane] = o;
}

// ---------------------------------------------------------------------------
// Output GEMM (att already normalized) with fused LN epilogue:
// ao = att @ Wo + bo ; ah = ffn + ao ; out = ah + LN(ah)*g + b
// ---------------------------------------------------------------------------
__global__ __launch_bounds__(256) void attn_out_k(
    const float* __restrict__ att,
    const float* __restrict__ Wo, const float* __restrict__ bo,
    const float* __restrict__ ffn, const float* __restrict__ g,
    const float* __restrict__ bln, float* __restrict__ Y, int M)
{
    __shared__ float xs[32][32];
    __shared__ float ws[32][128];
    const int tid  = threadIdx.x;
    const int row0 = blockIdx.x * 32;
    const int c0   = (tid & 31) * 4;
    const int r0   = (tid >> 5) * 4;
    const int lr   = tid >> 3;
    const int lk   = (tid & 7) * 4;
    const int wr   = tid >> 5;

    float acc[4][4];
    #pragma unroll
    for (int i = 0; i < 4; ++i)
        #pragma unroll
        for (int j = 0; j < 4; ++j) acc[i][j] = 0.f;

    for (int kt = 0; kt < OH; kt += 32) {
        float4 xv = f4zero();
        const int grow = row0 + lr;
        if (grow < M) xv = *(const float4*)&att[(size_t)grow * OH + kt + lk];
        xs[lk + 0][lr] = xv.x; xs[lk + 1][lr] = xv.y;
        xs[lk + 2][lr] = xv.z; xs[lk + 3][lr] = xv.w;
        #pragma unroll
        for (int j = 0; j < 4; ++j) {
            const int k = wr + 8 * j;
            *(float4*)&ws[k][c0] = *(const float4*)&Wo[(size_t)(kt + k) * OH + c0];
        }
        __syncthreads();
        #pragma unroll
        for (int k = 0; k < 32; ++k) {
            const float4 a = *(const float4*)&xs[k][r0];
            const float4 b = *(const float4*)&ws[k][c0];
            acc[0][0] += a.x*b.x; acc[0][1] += a.x*b.y; acc[0][2] += a.x*b.z; acc[0][3] += a.x*b.w;
            acc[1][0] += a.y*b.x; acc[1][1] += a.y*b.y; acc[1][2] += a.y*b.z; acc[1][3] += a.y*b.w;
            acc[2][0] += a.z*b.x; acc[2][1] += a.z*b.y; acc[2][2] += a.z*b.z; acc[2][3] += a.z*b.w;
            acc[3][0] += a.w*b.x; acc[3][1] += a.w*b.y; acc[3][2] += a.w*b.z; acc[3][3] += a.w*b.w;
        }
        __syncthreads();
    }

    const float4 bv = *(const float4*)&bo[c0];
    const float4 gv = *(const float4*)&g[c0];
    const float4 lv = *(const float4*)&bln[c0];

    #pragma unroll
    for (int i = 0; i < 4; ++i) {
        const int row = row0 + r0 + i;
        float4 f4 = f4zero();
        if (row < M) f4 = *(const float4*)&ffn[(size_t)row * OH + c0];
        float ah0 = acc[i][0] + bv.x + f4.x;
        float ah1 = acc[i][1] + bv.y + f4.y;
        float ah2 = acc[i][2] + bv.z + f4.z;
        float ah3 = acc[i][3] + bv.w + f4.w;
        float sum = ah0 + ah1 + ah2 + ah3;
        #pragma unroll
        for (int m = 16; m >= 1; m >>= 1) sum += __shfl_xor(sum, m, 32);
        const float mean = sum * (1.f / 128.f);
        const float d0 = ah0 - mean, d1 = ah1 - mean, d2 = ah2 - mean, d3 = ah3 - mean;
        float vs = d0*d0 + d1*d1 + d2*d2 + d3*d3;
        #pragma unroll
        for (int m = 16; m >= 1; m >>= 1) vs += __shfl_xor(vs, m, 32);
        const float inv = rsqrtf(vs * (1.f / 128.f) + 1e-5f);
        if (row < M) {
            float4 o;
            o.x = ah0 + d0 * inv * gv.x + lv.x;
            o.y = ah1 + d1 * inv * gv.y + lv.y;
            o.z = ah2 + d2 * inv * gv.z + lv.z;
            o.w = ah3 + d3 * inv * gv.w + lv.w;
            *(float4*)&Y[(size_t)row * OH + c0] = o;
        }
    }
}

// ---------------------------------------------------------------------------
extern "C" void kernel_launch(void* const* d_in, const int* in_sizes, int n_in,
                              void* d_out, int out_size, void* d_ws, size_t ws_size,
                              hipStream_t stream) {
    const float* x99   = (const float*)d_in[2];
    const float* feat0 = (const float*)d_in[3];
    const float* feat1 = (const float*)d_in[4];
    const float* Waq   = (const float*)d_in[10];
    const float* Wak   = (const float*)d_in[11];
    const float* Wav   = (const float*)d_in[12];
    const float* Wao   = (const float*)d_in[13];
    const float* Waffn = (const float*)d_in[14];
    const float* baq   = (const float*)d_in[20];
    const float* bak   = (const float*)d_in[21];
    const float* bav   = (const float*)d_in[22];
    const float* bao   = (const float*)d_in[23];
    const float* baffn = (const float*)d_in[24];
    const float* aln_b = (const float*)d_in[26];
    const float* aln_g = (const float*)d_in[28];
    const int* src0 = (const int*)d_in[29];
    const int* dst0 = (const int*)d_in[30];
    const int* src1 = (const int*)d_in[31];
    const int* dst1 = (const int*)d_in[32];

    float* q99 = (float*)d_ws;
    float* k99 = q99 + (size_t)NN * OH;
    float* v99 = k99 + (size_t)NN * OH;
    float* ffn = v99 + (size_t)NN * OH;
    float* att = ffn + (size_t)NN * OH;
    int*   cnt = (int*)(att + (size_t)NN * OH);   // NTOT
    int*   off = cnt + NTOT;                      // NTOT
    int*   bsum = off + NTOT;                     // SCANB (rounded up)

    float* out = (float*)d_out;
    // Park eidx (1.6M ints = 6.4 MB) in d_out's second half; it is consumed
    // (aggregate set1) before attn_out writes that region.
    int* eidx = (int*)(out + (size_t)NN * OH);

    const int gemm_grid = (NN + 31) / 32;
    gemm_bias_k<<<gemm_grid, 256, 0, stream>>>(x99, Waq,   baq,   q99, NN, AIN);
    gemm_bias_k<<<gemm_grid, 256, 0, stream>>>(x99, Wak,   bak,   k99, NN, AIN);
    gemm_bias_k<<<gemm_grid, 256, 0, stream>>>(x99, Wav,   bav,   v99, NN, AIN);
    gemm_bias_k<<<gemm_grid, 256, 0, stream>>>(x99, Waffn, baffn, ffn, NN, AIN);

    // CSR build (both edge sets at once)
    hipMemsetAsync(cnt, 0, NTOT * sizeof(int), stream);
    const int eg = (2 * EE + 255) / 256;
    hist_k<<<eg, 256, 0, stream>>>(dst0, dst1, cnt);
    scan1_k<<<SCANB, 256, 0, stream>>>(cnt, bsum);
    scan2_k<<<1, 128, 0, stream>>>(bsum);
    scan3_k<<<SCANB, 256, 0, stream>>>(cnt, bsum, off);
    scatter_k<<<eg, 256, 0, stream>>>(dst0, dst1, off, cnt, eidx);

    const int agg_grid = (NN + 3) / 4;

    // edge set 0
    aggregate_k<<<agg_grid, 256, 0, stream>>>(q99, k99, v99, src0, feat0, eidx, off, cnt, 0, att);
    attn_out_k<<<gemm_grid, 256, 0, stream>>>(att, Wao, bao, ffn, aln_g, aln_b, out, NN);

    // edge set 1
    aggregate_k<<<agg_grid, 256, 0, stream>>>(q99, k99, v99, src1, feat1, eidx, off, cnt, NN, att);
    attn_out_k<<<gemm_grid, 256, 0, stream>>>(att, Wao, bao, ffn, aln_g, aln_b, out + (size_t)NN * OH, NN);
}

// Round 4
// 725.908 us; speedup vs baseline: 1.7719x; 1.2885x over previous
//
#include <hip/hip_runtime.h>
#include <math.h>

#define NN 50000
#define EE 800000
#define AIN 256
#define OH 128
#define HH 4
#define DD 32

#define NTOT   (2 * NN)          // 100000 counters (set0 nodes, then set1 nodes)
#define NTOT4  (NTOT / 4)        // 25000 int4s
#define SCANB  ((NTOT4 + 255) / 256)   // 98 blocks

static __device__ __forceinline__ float4 f4zero() { float4 r; r.x=r.y=r.z=r.w=0.f; return r; }

// bf16 helpers (RNE pack, exact unpack)
static __device__ __forceinline__ unsigned short f2bf(float f) {
    union { float f; unsigned int u; } v; v.f = f;
    return (unsigned short)((v.u + 0x7FFFu + ((v.u >> 16) & 1u)) >> 16);
}
static __device__ __forceinline__ float bflo(unsigned int u) { return __uint_as_float(u << 16); }
static __device__ __forceinline__ float bfhi(unsigned int u) { return __uint_as_float(u & 0xFFFF0000u); }

// ---------------------------------------------------------------------------
// GEMM fp32 out: Y[M x 128] = X[M x K] @ W[K x 128] + bias. 32 rows/block.
// ---------------------------------------------------------------------------
__global__ __launch_bounds__(256) void gemm_bias_k(
    const float* __restrict__ X, const float* __restrict__ W,
    const float* __restrict__ bias, float* __restrict__ Y,
    int M, int K)
{
    __shared__ float xs[32][32];
    __shared__ float ws[32][128];
    const int tid  = threadIdx.x;
    const int row0 = blockIdx.x * 32;
    const int c0   = (tid & 31) * 4;
    const int r0   = (tid >> 5) * 4;
    const int lr   = tid >> 3;
    const int lk   = (tid & 7) * 4;
    const int wr   = tid >> 5;

    float acc[4][4];
    #pragma unroll
    for (int i = 0; i < 4; ++i)
        #pragma unroll
        for (int j = 0; j < 4; ++j) acc[i][j] = 0.f;

    for (int kt = 0; kt < K; kt += 32) {
        float4 xv = f4zero();
        const int grow = row0 + lr;
        if (grow < M) xv = *(const float4*)&X[(size_t)grow * K + kt + lk];
        xs[lk + 0][lr] = xv.x; xs[lk + 1][lr] = xv.y;
        xs[lk + 2][lr] = xv.z; xs[lk + 3][lr] = xv.w;
        #pragma unroll
        for (int j = 0; j < 4; ++j) {
            const int k = wr + 8 * j;
            *(float4*)&ws[k][c0] = *(const float4*)&W[(size_t)(kt + k) * OH + c0];
        }
        __syncthreads();
        #pragma unroll
        for (int k = 0; k < 32; ++k) {
            const float4 a = *(const float4*)&xs[k][r0];
            const float4 b = *(const float4*)&ws[k][c0];
            acc[0][0] += a.x*b.x; acc[0][1] += a.x*b.y; acc[0][2] += a.x*b.z; acc[0][3] += a.x*b.w;
            acc[1][0] += a.y*b.x; acc[1][1] += a.y*b.y; acc[1][2] += a.y*b.z; acc[1][3] += a.y*b.w;
            acc[2][0] += a.z*b.x; acc[2][1] += a.z*b.y; acc[2][2] += a.z*b.z; acc[2][3] += a.z*b.w;
            acc[3][0] += a.w*b.x; acc[3][1] += a.w*b.y; acc[3][2] += a.w*b.z; acc[3][3] += a.w*b.w;
        }
        __syncthreads();
    }

    const float4 bv = *(const float4*)&bias[c0];
    #pragma unroll
    for (int i = 0; i < 4; ++i) {
        const int row = row0 + r0 + i;
        if (row < M) {
            float4 o;
            o.x = acc[i][0] + bv.x; o.y = acc[i][1] + bv.y;
            o.z = acc[i][2] + bv.z; o.w = acc[i][3] + bv.w;
            *(float4*)&Y[(size_t)row * OH + c0] = o;
        }
    }
}

// ---------------------------------------------------------------------------
// GEMM bf16 out into interleaved kv rows: row stride 256 ushorts (512 B),
// k at colOff=0, v at colOff=128.
// ---------------------------------------------------------------------------
__global__ __launch_bounds__(256) void gemm_bias_bf16_k(
    const float* __restrict__ X, const float* __restrict__ W,
    const float* __restrict__ bias, unsigned short* __restrict__ Y,
    int colOff, int M, int K)
{
    __shared__ float xs[32][32];
    __shared__ float ws[32][128];
    const int tid  = threadIdx.x;
    const int row0 = blockIdx.x * 32;
    const int c0   = (tid & 31) * 4;
    const int r0   = (tid >> 5) * 4;
    const int lr   = tid >> 3;
    const int lk   = (tid & 7) * 4;
    const int wr   = tid >> 5;

    float acc[4][4];
    #pragma unroll
    for (int i = 0; i < 4; ++i)
        #pragma unroll
        for (int j = 0; j < 4; ++j) acc[i][j] = 0.f;

    for (int kt = 0; kt < K; kt += 32) {
        float4 xv = f4zero();
        const int grow = row0 + lr;
        if (grow < M) xv = *(const float4*)&X[(size_t)grow * K + kt + lk];
        xs[lk + 0][lr] = xv.x; xs[lk + 1][lr] = xv.y;
        xs[lk + 2][lr] = xv.z; xs[lk + 3][lr] = xv.w;
        #pragma unroll
        for (int j = 0; j < 4; ++j) {
            const int k = wr + 8 * j;
            *(float4*)&ws[k][c0] = *(const float4*)&W[(size_t)(kt + k) * OH + c0];
        }
        __syncthreads();
        #pragma unroll
        for (int k = 0; k < 32; ++k) {
            const float4 a = *(const float4*)&xs[k][r0];
            const float4 b = *(const float4*)&ws[k][c0];
            acc[0][0] += a.x*b.x; acc[0][1] += a.x*b.y; acc[0][2] += a.x*b.z; acc[0][3] += a.x*b.w;
            acc[1][0] += a.y*b.x; acc[1][1] += a.y*b.y; acc[1][2] += a.y*b.z; acc[1][3] += a.y*b.w;
            acc[2][0] += a.z*b.x; acc[2][1] += a.z*b.y; acc[2][2] += a.z*b.z; acc[2][3] += a.z*b.w;
            acc[3][0] += a.w*b.x; acc[3][1] += a.w*b.y; acc[3][2] += a.w*b.z; acc[3][3] += a.w*b.w;
        }
        __syncthreads();
    }

    const float4 bv = *(const float4*)&bias[c0];
    #pragma unroll
    for (int i = 0; i < 4; ++i) {
        const int row = row0 + r0 + i;
        if (row < M) {
            ushort4 o;
            o.x = f2bf(acc[i][0] + bv.x);
            o.y = f2bf(acc[i][1] + bv.y);
            o.z = f2bf(acc[i][2] + bv.z);
            o.w = f2bf(acc[i][3] + bv.w);
            *(ushort4*)&Y[(size_t)row * 256 + colOff + c0] = o;
        }
    }
}

// ---------------------------------------------------------------------------
// CSR build: histogram, two-level scan, scatter of packed {src, feat} records.
// ---------------------------------------------------------------------------
__global__ __launch_bounds__(256) void hist_k(
    const int* __restrict__ dst0, const int* __restrict__ dst1, int* __restrict__ cnt)
{
    const int i = blockIdx.x * 256 + threadIdx.x;
    if (i >= 2 * EE) return;
    const int d = (i < EE) ? dst0[i] : (NN + dst1[i - EE]);
    atomicAdd(&cnt[d], 1);
}

__global__ __launch_bounds__(256) void scan1_k(const int* __restrict__ cnt, int* __restrict__ bsum)
{
    __shared__ int part[256];
    const int t = threadIdx.x;
    const int i4 = blockIdx.x * 256 + t;
    int s = 0;
    if (i4 < NTOT4) {
        const int4 c = ((const int4*)cnt)[i4];
        s = c.x + c.y + c.z + c.w;
    }
    part[t] = s;
    __syncthreads();
    #pragma unroll
    for (int st = 128; st >= 1; st >>= 1) {
        if (t < st) part[t] += part[t + st];
        __syncthreads();
    }
    if (t == 0) bsum[blockIdx.x] = part[0];
}

__global__ __launch_bounds__(128) void scan2_k(int* __restrict__ bsum)
{
    __shared__ int part[128];
    const int t = threadIdx.x;
    int v = (t < SCANB) ? bsum[t] : 0;
    part[t] = v;
    __syncthreads();
    for (int st = 1; st < 128; st <<= 1) {
        int u = (t >= st) ? part[t - st] : 0;
        __syncthreads();
        part[t] += u;
        __syncthreads();
    }
    if (t < SCANB) bsum[t] = part[t] - v;
}

__global__ __launch_bounds__(256) void scan3_k(
    int* __restrict__ cnt, const int* __restrict__ bsum, int* __restrict__ off)
{
    __shared__ int part[256];
    const int t = threadIdx.x;
    const int i4 = blockIdx.x * 256 + t;
    int4 c = {0, 0, 0, 0};
    if (i4 < NTOT4) c = ((const int4*)cnt)[i4];
    const int s = c.x + c.y + c.z + c.w;
    part[t] = s;
    __syncthreads();
    for (int st = 1; st < 256; st <<= 1) {
        int u = (t >= st) ? part[t - st] : 0;
        __syncthreads();
        part[t] += u;
        __syncthreads();
    }
    if (i4 < NTOT4) {
        int base = bsum[blockIdx.x] + part[t] - s;
        int4 o;
        o.x = base;
        o.y = base + c.x;
        o.z = base + c.x + c.y;
        o.w = base + c.x + c.y + c.z;
        ((int4*)off)[i4] = o;
        ((int4*)cnt)[i4] = int4{0, 0, 0, 0};
    }
}

__global__ __launch_bounds__(256) void scatter_k(
    const int* __restrict__ dst0, const int* __restrict__ dst1,
    const int* __restrict__ src0, const int* __restrict__ src1,
    const float* __restrict__ feat0, const float* __restrict__ feat1,
    const int* __restrict__ off, int* __restrict__ cnt, int2* __restrict__ erec)
{
    const int i = blockIdx.x * 256 + threadIdx.x;
    if (i >= 2 * EE) return;
    const bool a = (i < EE);
    const int e = a ? i : (i - EE);
    const int d = a ? dst0[e] : (NN + dst1[e]);
    const int s = a ? src0[e] : src1[e];
    const float f = a ? feat0[(size_t)e * 2] : feat1[(size_t)e * 2];
    const int pos = off[d] + atomicAdd(&cnt[d], 1);
    int2 r; r.x = s; r.y = __float_as_int(f);
    erec[pos] = r;
}

// ---------------------------------------------------------------------------
// Per-destination aggregation: one wave per dst node. Records are broadcast
// from a single lane-vector load via __shfl (uniform index -> readlane, SGPR
// base gathers). kv rows are bf16 interleaved [k(256B)|v(256B)] = one 512 B
// contiguous gather per edge. Unroll 4 edges for MLP.
// ---------------------------------------------------------------------------
__global__ __launch_bounds__(256) void aggregate_k(
    const float* __restrict__ q99, const unsigned short* __restrict__ kv,
    const int2* __restrict__ erec,
    const int* __restrict__ off, const int* __restrict__ deg,
    int nodeBase, float* __restrict__ att)
{
    const int n = blockIdx.x * 4 + (threadIdx.x >> 6);
    if (n >= NN) return;
    const int lane = threadIdx.x & 63;
    const int start = off[nodeBase + n];
    const int count = deg[nodeBase + n];

    const float2 q2 = *(const float2*)&q99[(size_t)n * OH + 2 * lane];
    float accx = 0.f, accy = 0.f, z = 0.f;
    const float SCALE = 0.088388347648318447f;  // 1/sqrt(128)

    for (int base = 0; base < count; base += 64) {
        const int m = min(64, count - base);
        const int2 r = erec[start + base + min(lane, m - 1)];
        int j = 0;
        for (; j + 3 < m; j += 4) {
            const int s0 = __shfl(r.x, j);
            const int s1 = __shfl(r.x, j + 1);
            const int s2 = __shfl(r.x, j + 2);
            const int s3 = __shfl(r.x, j + 3);
            const float f0 = __int_as_float(__shfl(r.y, j));
            const float f1 = __int_as_float(__shfl(r.y, j + 1));
            const float f2 = __int_as_float(__shfl(r.y, j + 2));
            const float f3 = __int_as_float(__shfl(r.y, j + 3));
            const unsigned int ku0 = *(const unsigned int*)(kv + (size_t)s0 * 256 + 2 * lane);
            const unsigned int vu0 = *(const unsigned int*)(kv + (size_t)s0 * 256 + 128 + 2 * lane);
            const unsigned int ku1 = *(const unsigned int*)(kv + (size_t)s1 * 256 + 2 * lane);
            const unsigned int vu1 = *(const unsigned int*)(kv + (size_t)s1 * 256 + 128 + 2 * lane);
            const unsigned int ku2 = *(const unsigned int*)(kv + (size_t)s2 * 256 + 2 * lane);
            const unsigned int vu2 = *(const unsigned int*)(kv + (size_t)s2 * 256 + 128 + 2 * lane);
            const unsigned int ku3 = *(const unsigned int*)(kv + (size_t)s3 * 256 + 2 * lane);
            const unsigned int vu3 = *(const unsigned int*)(kv + (size_t)s3 * 256 + 128 + 2 * lane);

            float p0 = fmaf(bfhi(ku0), q2.y, bflo(ku0) * q2.x);
            float p1 = fmaf(bfhi(ku1), q2.y, bflo(ku1) * q2.x);
            float p2 = fmaf(bfhi(ku2), q2.y, bflo(ku2) * q2.x);
            float p3 = fmaf(bfhi(ku3), q2.y, bflo(ku3) * q2.x);
            #pragma unroll
            for (int mm = 8; mm >= 1; mm >>= 1) {
                p0 += __shfl_xor(p0, mm, 16);
                p1 += __shfl_xor(p1, mm, 16);
                p2 += __shfl_xor(p2, mm, 16);
                p3 += __shfl_xor(p3, mm, 16);
            }
            float sc0 = __expf(fminf(5.f, fmaxf(-5.f, p0 * f0 * SCALE)));
            float sc1 = __expf(fminf(5.f, fmaxf(-5.f, p1 * f1 * SCALE)));
            float sc2 = __expf(fminf(5.f, fmaxf(-5.f, p2 * f2 * SCALE)));
            float sc3 = __expf(fminf(5.f, fmaxf(-5.f, p3 * f3 * SCALE)));
            accx = fmaf(bflo(vu0), sc0, accx); accy = fmaf(bfhi(vu0), sc0, accy); z += sc0;
            accx = fmaf(bflo(vu1), sc1, accx); accy = fmaf(bfhi(vu1), sc1, accy); z += sc1;
            accx = fmaf(bflo(vu2), sc2, accx); accy = fmaf(bfhi(vu2), sc2, accy); z += sc2;
            accx = fmaf(bflo(vu3), sc3, accx); accy = fmaf(bfhi(vu3), sc3, accy); z += sc3;
        }
        for (; j < m; ++j) {
            const int s0 = __shfl(r.x, j);
            const float f0 = __int_as_float(__shfl(r.y, j));
            const unsigned int ku0 = *(const unsigned int*)(kv + (size_t)s0 * 256 + 2 * lane);
            const unsigned int vu0 = *(const unsigned int*)(kv + (size_t)s0 * 256 + 128 + 2 * lane);
            float p0 = fmaf(bfhi(ku0), q2.y, bflo(ku0) * q2.x);
            #pragma unroll
            for (int mm = 8; mm >= 1; mm >>= 1) p0 += __shfl_xor(p0, mm, 16);
            float sc0 = __expf(fminf(5.f, fmaxf(-5.f, p0 * f0 * SCALE)));
            accx = fmaf(bflo(vu0), sc0, accx); accy = fmaf(bfhi(vu0), sc0, accy); z += sc0;
        }
    }
    const float inv = 1.f / (z + 1.f);
    float2 o; o.x = accx * inv; o.y = accy * inv;
    *(float2*)&att[(size_t)n * OH + 2 * lane] = o;
}

// ---------------------------------------------------------------------------
// Output GEMM (att already normalized) with fused LN epilogue.
// ---------------------------------------------------------------------------
__global__ __launch_bounds__(256) void attn_out_k(
    const float* __restrict__ att,
    const float* __restrict__ Wo, const float* __restrict__ bo,
    const float* __restrict__ ffn, const float* __restrict__ g,
    const float* __restrict__ bln, float* __restrict__ Y, int M)
{
    __shared__ float xs[32][32];
    __shared__ float ws[32][128];
    const int tid  = threadIdx.x;
    const int row0 = blockIdx.x * 32;
    const int c0   = (tid & 31) * 4;
    const int r0   = (tid >> 5) * 4;
    const int lr   = tid >> 3;
    const int lk   = (tid & 7) * 4;
    const int wr   = tid >> 5;

    float acc[4][4];
    #pragma unroll
    for (int i = 0; i < 4; ++i)
        #pragma unroll
        for (int j = 0; j < 4; ++j) acc[i][j] = 0.f;

    for (int kt = 0; kt < OH; kt += 32) {
        float4 xv = f4zero();
        const int grow = row0 + lr;
        if (grow < M) xv = *(const float4*)&att[(size_t)grow * OH + kt + lk];
        xs[lk + 0][lr] = xv.x; xs[lk + 1][lr] = xv.y;
        xs[lk + 2][lr] = xv.z; xs[lk + 3][lr] = xv.w;
        #pragma unroll
        for (int j = 0; j < 4; ++j) {
            const int k = wr + 8 * j;
            *(float4*)&ws[k][c0] = *(const float4*)&Wo[(size_t)(kt + k) * OH + c0];
        }
        __syncthreads();
        #pragma unroll
        for (int k = 0; k < 32; ++k) {
            const float4 a = *(const float4*)&xs[k][r0];
            const float4 b = *(const float4*)&ws[k][c0];
            acc[0][0] += a.x*b.x; acc[0][1] += a.x*b.y; acc[0][2] += a.x*b.z; acc[0][3] += a.x*b.w;
            acc[1][0] += a.y*b.x; acc[1][1] += a.y*b.y; acc[1][2] += a.y*b.z; acc[1][3] += a.y*b.w;
            acc[2][0] += a.z*b.x; acc[2][1] += a.z*b.y; acc[2][2] += a.z*b.z; acc[2][3] += a.z*b.w;
            acc[3][0] += a.w*b.x; acc[3][1] += a.w*b.y; acc[3][2] += a.w*b.z; acc[3][3] += a.w*b.w;
        }
        __syncthreads();
    }

    const float4 bv = *(const float4*)&bo[c0];
    const float4 gv = *(const float4*)&g[c0];
    const float4 lv = *(const float4*)&bln[c0];

    #pragma unroll
    for (int i = 0; i < 4; ++i) {
        const int row = row0 + r0 + i;
        float4 f4 = f4zero();
        if (row < M) f4 = *(const float4*)&ffn[(size_t)row * OH + c0];
        float ah0 = acc[i][0] + bv.x + f4.x;
        float ah1 = acc[i][1] + bv.y + f4.y;
        float ah2 = acc[i][2] + bv.z + f4.z;
        float ah3 = acc[i][3] + bv.w + f4.w;
        float sum = ah0 + ah1 + ah2 + ah3;
        #pragma unroll
        for (int m = 16; m >= 1; m >>= 1) sum += __shfl_xor(sum, m, 32);
        const float mean = sum * (1.f / 128.f);
        const float d0 = ah0 - mean, d1 = ah1 - mean, d2 = ah2 - mean, d3 = ah3 - mean;
        float vs = d0*d0 + d1*d1 + d2*d2 + d3*d3;
        #pragma unroll
        for (int m = 16; m >= 1; m >>= 1) vs += __shfl_xor(vs, m, 32);
        const float inv = rsqrtf(vs * (1.f / 128.f) + 1e-5f);
        if (row < M) {
            float4 o;
            o.x = ah0 + d0 * inv * gv.x + lv.x;
            o.y = ah1 + d1 * inv * gv.y + lv.y;
            o.z = ah2 + d2 * inv * gv.z + lv.z;
            o.w = ah3 + d3 * inv * gv.w + lv.w;
            *(float4*)&Y[(size_t)row * OH + c0] = o;
        }
    }
}

// ---------------------------------------------------------------------------
extern "C" void kernel_launch(void* const* d_in, const int* in_sizes, int n_in,
                              void* d_out, int out_size, void* d_ws, size_t ws_size,
                              hipStream_t stream) {
    const float* x99   = (const float*)d_in[2];
    const float* feat0 = (const float*)d_in[3];
    const float* feat1 = (const float*)d_in[4];
    const float* Waq   = (const float*)d_in[10];
    const float* Wak   = (const float*)d_in[11];
    const float* Wav   = (const float*)d_in[12];
    const float* Wao   = (const float*)d_in[13];
    const float* Waffn = (const float*)d_in[14];
    const float* baq   = (const float*)d_in[20];
    const float* bak   = (const float*)d_in[21];
    const float* bav   = (const float*)d_in[22];
    const float* bao   = (const float*)d_in[23];
    const float* baffn = (const float*)d_in[24];
    const float* aln_b = (const float*)d_in[26];
    const float* aln_g = (const float*)d_in[28];
    const int* src0 = (const int*)d_in[29];
    const int* dst0 = (const int*)d_in[30];
    const int* src1 = (const int*)d_in[31];
    const int* dst1 = (const int*)d_in[32];

    float* q99 = (float*)d_ws;                              // NN*128 f
    float* ffn = q99 + (size_t)NN * OH;                     // NN*128 f
    float* att = ffn + (size_t)NN * OH;                     // NN*128 f
    unsigned short* kv = (unsigned short*)(att + (size_t)NN * OH);  // NN*256 us
    int2* erec = (int2*)(kv + (size_t)NN * 256);            // 2*EE int2
    int*  cnt  = (int*)(erec + (size_t)2 * EE);             // NTOT
    int*  off  = cnt + NTOT;                                // NTOT
    int*  bsum = off + NTOT;                                // SCANB

    float* out = (float*)d_out;

    const int gemm_grid = (NN + 31) / 32;
    gemm_bias_k<<<gemm_grid, 256, 0, stream>>>(x99, Waq, baq, q99, NN, AIN);
    gemm_bias_bf16_k<<<gemm_grid, 256, 0, stream>>>(x99, Wak, bak, kv, 0,   NN, AIN);
    gemm_bias_bf16_k<<<gemm_grid, 256, 0, stream>>>(x99, Wav, bav, kv, 128, NN, AIN);
    gemm_bias_k<<<gemm_grid, 256, 0, stream>>>(x99, Waffn, baffn, ffn, NN, AIN);

    // CSR build (both edge sets at once)
    hipMemsetAsync(cnt, 0, NTOT * sizeof(int), stream);
    const int eg = (2 * EE + 255) / 256;
    hist_k<<<eg, 256, 0, stream>>>(dst0, dst1, cnt);
    scan1_k<<<SCANB, 256, 0, stream>>>(cnt, bsum);
    scan2_k<<<1, 128, 0, stream>>>(bsum);
    scan3_k<<<SCANB, 256, 0, stream>>>(cnt, bsum, off);
    scatter_k<<<eg, 256, 0, stream>>>(dst0, dst1, src0, src1, feat0, feat1, off, cnt, erec);

    const int agg_grid = (NN + 3) / 4;

    // edge set 0
    aggregate_k<<<agg_grid, 256, 0, stream>>>(q99, kv, erec, off, cnt, 0, att);
    attn_out_k<<<gemm_grid, 256, 0, stream>>>(att, Wao, bao, ffn, aln_g, aln_b, out, NN);

    // edge set 1
    aggregate_k<<<agg_grid, 256, 0, stream>>>(q99, kv, erec, off, cnt, NN, att);
    attn_out_k<<<gemm_grid, 256, 0, stream>>>(att, Wao, bao, ffn, aln_g, aln_b, out + (size_t)NN * OH, NN);
}

// Round 5
// 564.032 us; speedup vs baseline: 2.2804x; 1.2870x over previous
//
#include <hip/hip_runtime.h>
#include <math.h>

#define NN 50000
#define EE 800000
#define AIN 256
#define OH 128
#define HH 4

#define NTOT   (2 * NN)
#define NTOT4  (NTOT / 4)
#define SCANB  ((NTOT4 + 255) / 256)   // 98

typedef __attribute__((ext_vector_type(8))) short bf16x8;
typedef __attribute__((ext_vector_type(4))) float f32x4;

static __device__ __forceinline__ unsigned short f2bf(float f) {
    union { float f; unsigned int u; } v; v.f = f;
    return (unsigned short)((v.u + 0x7FFFu + ((v.u >> 16) & 1u)) >> 16);
}
static __device__ __forceinline__ float bflo(unsigned int u) { return __uint_as_float(u << 16); }
static __device__ __forceinline__ float bfhi(unsigned int u) { return __uint_as_float(u & 0xFFFF0000u); }

// ---------------------------------------------------------------------------
// x99 fp32 -> bf16
// ---------------------------------------------------------------------------
__global__ __launch_bounds__(256) void cvt_x_k(const float* __restrict__ x, unsigned short* __restrict__ xb)
{
    const int i = blockIdx.x * 256 + threadIdx.x;   // float4 units
    if (i >= NN * AIN / 4) return;
    const float4 v = ((const float4*)x)[i];
    ushort4 o;
    o.x = f2bf(v.x); o.y = f2bf(v.y); o.z = f2bf(v.z); o.w = f2bf(v.w);
    ((ushort4*)xb)[i] = o;
}

// ---------------------------------------------------------------------------
// Weights -> bf16, transposed to [n][k] (n-major) for MFMA B-frags.
// blocks 0..511: QKVF concat (n = 128*y + col), K=256. blocks 512..639: Wao, K=128.
// ---------------------------------------------------------------------------
__global__ __launch_bounds__(256) void cvt_w_k(
    const float* __restrict__ Wq, const float* __restrict__ Wk,
    const float* __restrict__ Wv, const float* __restrict__ Wf,
    const float* __restrict__ Wo, unsigned short* __restrict__ Wt,
    unsigned short* __restrict__ Waot)
{
    const int n = blockIdx.x;
    const int k = threadIdx.x;
    if (n < 512) {
        const float* W = (n < 128) ? Wq : (n < 256) ? Wk : (n < 384) ? Wv : Wf;
        Wt[(size_t)n * 256 + k] = f2bf(W[(size_t)k * OH + (n & 127)]);
    } else {
        if (k < 128) Waot[(size_t)(n - 512) * 128 + k] = f2bf(Wo[(size_t)k * OH + (n - 512)]);
    }
}

// ---------------------------------------------------------------------------
// Fused QKV+FFN GEMM, bf16 MFMA 16x16x32. 128x128 tile, BK=32, 4 waves.
// blockIdx.y selects weight matrix 0..3 (q, k, v, ffn).
// ---------------------------------------------------------------------------
__global__ __launch_bounds__(256) void qkvf_mfma_k(
    const unsigned short* __restrict__ xb,   // [M][256] bf16
    const unsigned short* __restrict__ Wt,   // [512][256] bf16 n-major
    const float* __restrict__ bq, const float* __restrict__ bk,
    const float* __restrict__ bv, const float* __restrict__ bf,
    unsigned short* __restrict__ qb, unsigned short* __restrict__ kv,
    unsigned short* __restrict__ ffnb, int M)
{
    __shared__ unsigned short As[128][40];
    __shared__ unsigned short Bs[128][40];
    const int tid  = threadIdx.x;
    const int lane = tid & 63;
    const int wave = tid >> 6;
    const int wr = wave >> 1, wc = wave & 1;
    const int quad = lane >> 4, m16 = lane & 15;
    const int row0 = blockIdx.x * 128;
    const int col0 = blockIdx.y * 128;

    f32x4 acc[4][4];
    #pragma unroll
    for (int i = 0; i < 4; ++i)
        #pragma unroll
        for (int j = 0; j < 4; ++j) acc[i][j] = 0.f;

    const int lr  = tid >> 1;
    const int lkh = (tid & 1) * 16;

    for (int kt = 0; kt < 256; kt += 32) {
        uint4 a0 = {0,0,0,0}, a1 = {0,0,0,0};
        const int grow = row0 + lr;
        if (grow < M) {
            const uint4* p = (const uint4*)(xb + (size_t)grow * 256 + kt + lkh);
            a0 = p[0]; a1 = p[1];
        }
        *(uint4*)&As[lr][lkh]     = a0;
        *(uint4*)&As[lr][lkh + 8] = a1;
        const uint4* wp = (const uint4*)(Wt + (size_t)(col0 + lr) * 256 + kt + lkh);
        *(uint4*)&Bs[lr][lkh]     = wp[0];
        *(uint4*)&Bs[lr][lkh + 8] = wp[1];
        __syncthreads();
        bf16x8 af[4], bfr[4];
        #pragma unroll
        for (int t = 0; t < 4; ++t) af[t]  = *(const bf16x8*)&As[wr * 64 + t * 16 + m16][quad * 8];
        #pragma unroll
        for (int t = 0; t < 4; ++t) bfr[t] = *(const bf16x8*)&Bs[wc * 64 + t * 16 + m16][quad * 8];
        #pragma unroll
        for (int i = 0; i < 4; ++i)
            #pragma unroll
            for (int j = 0; j < 4; ++j)
                acc[i][j] = __builtin_amdgcn_mfma_f32_16x16x32_bf16(af[i], bfr[j], acc[i][j], 0, 0, 0);
        __syncthreads();
    }

    const int y = blockIdx.y;
    const float* bias = (y == 0) ? bq : (y == 1) ? bk : (y == 2) ? bv : bf;
    unsigned short* obase = (y == 0) ? qb : (y == 3) ? ffnb : kv;
    const int ostride = (y == 1 || y == 2) ? 256 : 128;
    const int ocol    = (y == 2) ? 128 : 0;

    #pragma unroll
    for (int i = 0; i < 4; ++i) {
        #pragma unroll
        for (int j = 0; j < 4; ++j) {
            const int col = wc * 64 + j * 16 + m16;
            const float b = bias[col];
            #pragma unroll
            for (int r = 0; r < 4; ++r) {
                const int row = row0 + wr * 64 + i * 16 + quad * 4 + r;
                if (row < M) obase[(size_t)row * ostride + ocol + col] = f2bf(acc[i][j][r] + b);
            }
        }
    }
}

// ---------------------------------------------------------------------------
// CSR build
// ---------------------------------------------------------------------------
__global__ __launch_bounds__(256) void hist_k(
    const int* __restrict__ dst0, const int* __restrict__ dst1, int* __restrict__ cnt)
{
    const int i = blockIdx.x * 256 + threadIdx.x;
    if (i >= 2 * EE) return;
    const int d = (i < EE) ? dst0[i] : (NN + dst1[i - EE]);
    atomicAdd(&cnt[d], 1);
}

__global__ __launch_bounds__(256) void scan1_k(const int* __restrict__ cnt, int* __restrict__ bsum)
{
    __shared__ int part[256];
    const int t = threadIdx.x;
    const int i4 = blockIdx.x * 256 + t;
    int s = 0;
    if (i4 < NTOT4) {
        const int4 c = ((const int4*)cnt)[i4];
        s = c.x + c.y + c.z + c.w;
    }
    part[t] = s;
    __syncthreads();
    #pragma unroll
    for (int st = 128; st >= 1; st >>= 1) {
        if (t < st) part[t] += part[t + st];
        __syncthreads();
    }
    if (t == 0) bsum[blockIdx.x] = part[0];
}

__global__ __launch_bounds__(128) void scan2_k(int* __restrict__ bsum)
{
    __shared__ int part[128];
    const int t = threadIdx.x;
    int v = (t < SCANB) ? bsum[t] : 0;
    part[t] = v;
    __syncthreads();
    for (int st = 1; st < 128; st <<= 1) {
        int u = (t >= st) ? part[t - st] : 0;
        __syncthreads();
        part[t] += u;
        __syncthreads();
    }
    if (t < SCANB) bsum[t] = part[t] - v;
}

__global__ __launch_bounds__(256) void scan3_k(
    int* __restrict__ cnt, const int* __restrict__ bsum, int* __restrict__ off)
{
    __shared__ int part[256];
    const int t = threadIdx.x;
    const int i4 = blockIdx.x * 256 + t;
    int4 c = {0, 0, 0, 0};
    if (i4 < NTOT4) c = ((const int4*)cnt)[i4];
    const int s = c.x + c.y + c.z + c.w;
    part[t] = s;
    __syncthreads();
    for (int st = 1; st < 256; st <<= 1) {
        int u = (t >= st) ? part[t - st] : 0;
        __syncthreads();
        part[t] += u;
        __syncthreads();
    }
    if (i4 < NTOT4) {
        int base = bsum[blockIdx.x] + part[t] - s;
        int4 o;
        o.x = base;
        o.y = base + c.x;
        o.z = base + c.x + c.y;
        o.w = base + c.x + c.y + c.z;
        ((int4*)off)[i4] = o;
        ((int4*)cnt)[i4] = int4{0, 0, 0, 0};
    }
}

// 4 edges per thread (grid-stride): 4 independent atomic->write chains in flight.
// Record = (src << 16) | bf16(feat)  [src < 65536].
__global__ __launch_bounds__(256) void scatter_k(
    const int* __restrict__ dst0, const int* __restrict__ dst1,
    const int* __restrict__ src0, const int* __restrict__ src1,
    const float* __restrict__ feat0, const float* __restrict__ feat1,
    const int* __restrict__ off, int* __restrict__ cnt, unsigned int* __restrict__ erec)
{
    const int T = gridDim.x * 256;
    int i = blockIdx.x * 256 + threadIdx.x;
    #pragma unroll
    for (int u = 0; u < 4; ++u, i += T) {
        if (i < 2 * EE) {
            const bool a = (i < EE);
            const int e = a ? i : (i - EE);
            const int d = a ? dst0[e] : (NN + dst1[e]);
            const int s = a ? src0[e] : src1[e];
            const float f = a ? feat0[(size_t)e * 2] : feat1[(size_t)e * 2];
            const int pos = off[d] + atomicAdd(&cnt[d], 1);
            erec[pos] = ((unsigned int)s << 16) | (unsigned int)f2bf(f);
        }
    }
}

// ---------------------------------------------------------------------------
// Per-destination aggregation: one wave per dst node; 4 B records broadcast
// via shfl; bf16 kv gather (one 512 B contiguous region per edge); bf16 q.
// Writes att bf16.
// ---------------------------------------------------------------------------
__global__ __launch_bounds__(256) void aggregate_k(
    const unsigned short* __restrict__ qb, const unsigned short* __restrict__ kv,
    const unsigned int* __restrict__ erec,
    const int* __restrict__ off, const int* __restrict__ deg,
    int nodeBase, unsigned short* __restrict__ att)
{
    const int n = blockIdx.x * 4 + (threadIdx.x >> 6);
    if (n >= NN) return;
    const int lane = threadIdx.x & 63;
    const int start = off[nodeBase + n];
    const int count = deg[nodeBase + n];

    const unsigned int qu = *(const unsigned int*)(qb + (size_t)n * 128 + 2 * lane);
    const float qx = bflo(qu), qy = bfhi(qu);

    float accx = 0.f, accy = 0.f, z = 0.f;
    const float SCALE = 0.088388347648318447f;  // 1/sqrt(128)

    for (int base = 0; base < count; base += 64) {
        const int m = min(64, count - base);
        const unsigned int rr = erec[start + base + min(lane, m - 1)];
        int j = 0;
        for (; j + 3 < m; j += 4) {
            const unsigned int r0 = (unsigned int)__shfl((int)rr, j);
            const unsigned int r1 = (unsigned int)__shfl((int)rr, j + 1);
            const unsigned int r2 = (unsigned int)__shfl((int)rr, j + 2);
            const unsigned int r3 = (unsigned int)__shfl((int)rr, j + 3);
            const int s0 = r0 >> 16, s1 = r1 >> 16, s2 = r2 >> 16, s3 = r3 >> 16;
            const float f0 = bflo(r0 & 0xFFFFu) , f1 = bflo(r1 & 0xFFFFu),
                        f2 = bflo(r2 & 0xFFFFu) , f3 = bflo(r3 & 0xFFFFu);
            const unsigned int ku0 = *(const unsigned int*)(kv + (size_t)s0 * 256 + 2 * lane);
            const unsigned int vu0 = *(const unsigned int*)(kv + (size_t)s0 * 256 + 128 + 2 * lane);
            const unsigned int ku1 = *(const unsigned int*)(kv + (size_t)s1 * 256 + 2 * lane);
            const unsigned int vu1 = *(const unsigned int*)(kv + (size_t)s1 * 256 + 128 + 2 * lane);
            const unsigned int ku2 = *(const unsigned int*)(kv + (size_t)s2 * 256 + 2 * lane);
            const unsigned int vu2 = *(const unsigned int*)(kv + (size_t)s2 * 256 + 128 + 2 * lane);
            const unsigned int ku3 = *(const unsigned int*)(kv + (size_t)s3 * 256 + 2 * lane);
            const unsigned int vu3 = *(const unsigned int*)(kv + (size_t)s3 * 256 + 128 + 2 * lane);

            float p0 = fmaf(bfhi(ku0), qy, bflo(ku0) * qx);
            float p1 = fmaf(bfhi(ku1), qy, bflo(ku1) * qx);
            float p2 = fmaf(bfhi(ku2), qy, bflo(ku2) * qx);
            float p3 = fmaf(bfhi(ku3), qy, bflo(ku3) * qx);
            #pragma unroll
            for (int mm = 8; mm >= 1; mm >>= 1) {
                p0 += __shfl_xor(p0, mm, 16);
                p1 += __shfl_xor(p1, mm, 16);
                p2 += __shfl_xor(p2, mm, 16);
                p3 += __shfl_xor(p3, mm, 16);
            }
            float sc0 = __expf(fminf(5.f, fmaxf(-5.f, p0 * f0 * SCALE)));
            float sc1 = __expf(fminf(5.f, fmaxf(-5.f, p1 * f1 * SCALE)));
            float sc2 = __expf(fminf(5.f, fmaxf(-5.f, p2 * f2 * SCALE)));
            float sc3 = __expf(fminf(5.f, fmaxf(-5.f, p3 * f3 * SCALE)));
            accx = fmaf(bflo(vu0), sc0, accx); accy = fmaf(bfhi(vu0), sc0, accy); z += sc0;
            accx = fmaf(bflo(vu1), sc1, accx); accy = fmaf(bfhi(vu1), sc1, accy); z += sc1;
            accx = fmaf(bflo(vu2), sc2, accx); accy = fmaf(bfhi(vu2), sc2, accy); z += sc2;
            accx = fmaf(bflo(vu3), sc3, accx); accy = fmaf(bfhi(vu3), sc3, accy); z += sc3;
        }
        for (; j < m; ++j) {
            const unsigned int r0 = (unsigned int)__shfl((int)rr, j);
            const int s0 = r0 >> 16;
            const float f0 = bflo(r0 & 0xFFFFu);
            const unsigned int ku0 = *(const unsigned int*)(kv + (size_t)s0 * 256 + 2 * lane);
            const unsigned int vu0 = *(const unsigned int*)(kv + (size_t)s0 * 256 + 128 + 2 * lane);
            float p0 = fmaf(bfhi(ku0), qy, bflo(ku0) * qx);
            #pragma unroll
            for (int mm = 8; mm >= 1; mm >>= 1) p0 += __shfl_xor(p0, mm, 16);
            float sc0 = __expf(fminf(5.f, fmaxf(-5.f, p0 * f0 * SCALE)));
            accx = fmaf(bflo(vu0), sc0, accx); accy = fmaf(bfhi(vu0), sc0, accy); z += sc0;
        }
    }
    const float inv = 1.f / (z + 1.f);
    const unsigned int o = ((unsigned int)f2bf(accy * inv) << 16) | (unsigned int)f2bf(accx * inv);
    *(unsigned int*)(att + (size_t)n * 128 + 2 * lane) = o;
}

// ---------------------------------------------------------------------------
// Output GEMM: att[Mx128]bf16 @ Waot -> + bo + ffn, LN epilogue via LDS.
// ---------------------------------------------------------------------------
__global__ __launch_bounds__(256) void attn_out_mfma_k(
    const unsigned short* __restrict__ att, const unsigned short* __restrict__ Wt,
    const float* __restrict__ bo, const unsigned short* __restrict__ ffnb,
    const float* __restrict__ g, const float* __restrict__ bln,
    float* __restrict__ Y, int M)
{
    __shared__ __align__(16) char lds[128 * 138 * 2];   // 35328 B
    unsigned short (*As)[40] = (unsigned short(*)[40])lds;
    unsigned short (*Bs)[40] = (unsigned short(*)[40])(lds + 128 * 40 * 2);
    unsigned short (*sh)[138] = (unsigned short(*)[138])lds;

    const int tid  = threadIdx.x;
    const int lane = tid & 63;
    const int wave = tid >> 6;
    const int wr = wave >> 1, wc = wave & 1;
    const int quad = lane >> 4, m16 = lane & 15;
    const int row0 = blockIdx.x * 128;

    f32x4 acc[4][4];
    #pragma unroll
    for (int i = 0; i < 4; ++i)
        #pragma unroll
        for (int j = 0; j < 4; ++j) acc[i][j] = 0.f;

    const int lr  = tid >> 1;
    const int lkh = (tid & 1) * 16;

    for (int kt = 0; kt < 128; kt += 32) {
        uint4 a0 = {0,0,0,0}, a1 = {0,0,0,0};
        const int grow = row0 + lr;
        if (grow < M) {
            const uint4* p = (const uint4*)(att + (size_t)grow * 128 + kt + lkh);
            a0 = p[0]; a1 = p[1];
        }
        *(uint4*)&As[lr][lkh]     = a0;
        *(uint4*)&As[lr][lkh + 8] = a1;
        const uint4* wp = (const uint4*)(Wt + (size_t)lr * 128 + kt + lkh);
        *(uint4*)&Bs[lr][lkh]     = wp[0];
        *(uint4*)&Bs[lr][lkh + 8] = wp[1];
        __syncthreads();
        bf16x8 af[4], bfr[4];
        #pragma unroll
        for (int t = 0; t < 4; ++t) af[t]  = *(const bf16x8*)&As[wr * 64 + t * 16 + m16][quad * 8];
        #pragma unroll
        for (int t = 0; t < 4; ++t) bfr[t] = *(const bf16x8*)&Bs[wc * 64 + t * 16 + m16][quad * 8];
        #pragma unroll
        for (int i = 0; i < 4; ++i)
            #pragma unroll
            for (int j = 0; j < 4; ++j)
                acc[i][j] = __builtin_amdgcn_mfma_f32_16x16x32_bf16(af[i], bfr[j], acc[i][j], 0, 0, 0);
        __syncthreads();
    }

    // ah = C + bo + ffn  -> sh (bf16)
    #pragma unroll
    for (int i = 0; i < 4; ++i) {
        #pragma unroll
        for (int j = 0; j < 4; ++j) {
            const int col = wc * 64 + j * 16 + m16;
            const float b = bo[col];
            #pragma unroll
            for (int r = 0; r < 4; ++r) {
                const int rl = wr * 64 + i * 16 + quad * 4 + r;
                const int grow = row0 + rl;
                float ffv = 0.f;
                if (grow < M) ffv = bflo(ffnb[(size_t)grow * 128 + col]);
                sh[rl][col] = f2bf(acc[i][j][r] + b + ffv);
            }
        }
    }
    __syncthreads();

    // LN: thread t (<128) handles row t
    if (tid < 128) {
        const int grow = row0 + tid;
        if (grow < M) {
            float sum = 0.f, sq = 0.f;
            #pragma unroll
            for (int j = 0; j < 128; j += 2) {
                const unsigned int u = *(const unsigned int*)&sh[tid][j];
                const float a = bflo(u), bb = bfhi(u);
                sum += a + bb;
                sq  += a * a + bb * bb;
            }
            const float mean = sum * (1.f / 128.f);
            const float var  = sq * (1.f / 128.f) - mean * mean;
            const float inv  = rsqrtf(fmaxf(var, 0.f) + 1e-5f);
            float* yrow = Y + (size_t)grow * 128;
            #pragma unroll
            for (int j = 0; j < 128; j += 4) {
                const unsigned int u0 = *(const unsigned int*)&sh[tid][j];
                const unsigned int u1 = *(const unsigned int*)&sh[tid][j + 2];
                const float4 gv = *(const float4*)&g[j];
                const float4 lv = *(const float4*)&bln[j];
                float4 o;
                const float x0 = bflo(u0), x1 = bfhi(u0), x2 = bflo(u1), x3 = bfhi(u1);
                o.x = x0 + (x0 - mean) * inv * gv.x + lv.x;
                o.y = x1 + (x1 - mean) * inv * gv.y + lv.y;
                o.z = x2 + (x2 - mean) * inv * gv.z + lv.z;
                o.w = x3 + (x3 - mean) * inv * gv.w + lv.w;
                *(float4*)&yrow[j] = o;
            }
        }
    }
}

// ---------------------------------------------------------------------------
extern "C" void kernel_launch(void* const* d_in, const int* in_sizes, int n_in,
                              void* d_out, int out_size, void* d_ws, size_t ws_size,
                              hipStream_t stream) {
    const float* x99   = (const float*)d_in[2];
    const float* feat0 = (const float*)d_in[3];
    const float* feat1 = (const float*)d_in[4];
    const float* Waq   = (const float*)d_in[10];
    const float* Wak   = (const float*)d_in[11];
    const float* Wav   = (const float*)d_in[12];
    const float* Wao   = (const float*)d_in[13];
    const float* Waffn = (const float*)d_in[14];
    const float* baq   = (const float*)d_in[20];
    const float* bak   = (const float*)d_in[21];
    const float* bav   = (const float*)d_in[22];
    const float* bao   = (const float*)d_in[23];
    const float* baffn = (const float*)d_in[24];
    const float* aln_b = (const float*)d_in[26];
    const float* aln_g = (const float*)d_in[28];
    const int* src0 = (const int*)d_in[29];
    const int* dst0 = (const int*)d_in[30];
    const int* src1 = (const int*)d_in[31];
    const int* dst1 = (const int*)d_in[32];

    unsigned short* xb   = (unsigned short*)d_ws;                 // NN*256
    unsigned short* qb   = xb   + (size_t)NN * 256;               // NN*128
    unsigned short* kv   = qb   + (size_t)NN * 128;               // NN*256
    unsigned short* ffnb = kv   + (size_t)NN * 256;               // NN*128
    unsigned short* att  = ffnb + (size_t)NN * 128;               // NN*128
    unsigned short* Wt   = att  + (size_t)NN * 128;               // 512*256
    unsigned short* Waot = Wt   + (size_t)512 * 256;              // 128*128
    unsigned int*   erec = (unsigned int*)(Waot + 128 * 128);     // 2*EE
    int* cnt  = (int*)(erec + (size_t)2 * EE);                    // NTOT
    int* off  = cnt + NTOT;                                       // NTOT
    int* bsum = off + NTOT;

    float* out = (float*)d_out;

    cvt_x_k<<<(NN * AIN / 4 + 255) / 256, 256, 0, stream>>>(x99, xb);
    cvt_w_k<<<640, 256, 0, stream>>>(Waq, Wak, Wav, Waffn, Wao, Wt, Waot);

    const int mtiles = (NN + 127) / 128;   // 391
    qkvf_mfma_k<<<dim3(mtiles, 4), 256, 0, stream>>>(xb, Wt, baq, bak, bav, baffn, qb, kv, ffnb, NN);

    // CSR build
    hipMemsetAsync(cnt, 0, NTOT * sizeof(int), stream);
    const int eg = (2 * EE + 255) / 256;
    hist_k<<<eg, 256, 0, stream>>>(dst0, dst1, cnt);
    scan1_k<<<SCANB, 256, 0, stream>>>(cnt, bsum);
    scan2_k<<<1, 128, 0, stream>>>(bsum);
    scan3_k<<<SCANB, 256, 0, stream>>>(cnt, bsum, off);
    scatter_k<<<(2 * EE / 4 + 255) / 256, 256, 0, stream>>>(
        dst0, dst1, src0, src1, feat0, feat1, off, cnt, erec);

    const int agg_grid = (NN + 3) / 4;

    aggregate_k<<<agg_grid, 256, 0, stream>>>(qb, kv, erec, off, cnt, 0, att);
    attn_out_mfma_k<<<mtiles, 256, 0, stream>>>(att, Waot, bao, ffnb, aln_g, aln_b, out, NN);

    aggregate_k<<<agg_grid, 256, 0, stream>>>(qb, kv, erec, off, cnt, NN, att);
    attn_out_mfma_k<<<mtiles, 256, 0, stream>>>(att, Waot, bao, ffnb, aln_g, aln_b, out + (size_t)NN * OH, NN);
}

// Round 7
// 478.401 us; speedup vs baseline: 2.6886x; 1.1790x over previous
//
#include <hip/hip_runtime.h>
#include <math.h>

#define NN 50000
#define EE 800000
#define AIN 256
#define OH 128

#define NTOT  (2 * NN)        // combined node ids: set0 = [0,NN), set1 = [NN,2NN)
#define NB    391             // buckets of 256 nodes
#define CAP   5120            // per-bucket stage capacity (mean 4092, +16 sigma)

typedef __attribute__((ext_vector_type(8))) short bf16x8;
typedef __attribute__((ext_vector_type(4))) float f32x4;

static __device__ __forceinline__ unsigned short f2bf(float f) {
    union { float f; unsigned int u; } v; v.f = f;
    return (unsigned short)((v.u + 0x7FFFu + ((v.u >> 16) & 1u)) >> 16);
}
static __device__ __forceinline__ float bflo(unsigned int u) { return __uint_as_float(u << 16); }
static __device__ __forceinline__ float bfhi(unsigned int u) { return __uint_as_float(u & 0xFFFF0000u); }

// ---------------------------------------------------------------------------
__global__ __launch_bounds__(256) void cvt_x_k(const float* __restrict__ x, unsigned short* __restrict__ xb)
{
    const int i = blockIdx.x * 256 + threadIdx.x;
    if (i >= NN * AIN / 4) return;
    const float4 v = ((const float4*)x)[i];
    ushort4 o;
    o.x = f2bf(v.x); o.y = f2bf(v.y); o.z = f2bf(v.z); o.w = f2bf(v.w);
    ((ushort4*)xb)[i] = o;
}

__global__ __launch_bounds__(256) void cvt_w_k(
    const float* __restrict__ Wq, const float* __restrict__ Wk,
    const float* __restrict__ Wv, const float* __restrict__ Wf,
    const float* __restrict__ Wo, unsigned short* __restrict__ Wt,
    unsigned short* __restrict__ Waot)
{
    const int n = blockIdx.x;
    const int k = threadIdx.x;
    if (n < 512) {
        const float* W = (n < 128) ? Wq : (n < 256) ? Wk : (n < 384) ? Wv : Wf;
        Wt[(size_t)n * 256 + k] = f2bf(W[(size_t)k * OH + (n & 127)]);
    } else {
        if (k < 128) Waot[(size_t)(n - 512) * 128 + k] = f2bf(Wo[(size_t)k * OH + (n - 512)]);
    }
}

// ---------------------------------------------------------------------------
// Fused QKV+FFN GEMM, bf16 MFMA 16x16x32. 128x128 tile, BK=32, 4 waves.
// y=0 -> q (fp32 out), y=1 -> k (bf16 into kv col 0), y=2 -> v (bf16 kv col
// 128), y=3 -> ffn (bf16).
// ---------------------------------------------------------------------------
__global__ __launch_bounds__(256) void qkvf_mfma_k(
    const unsigned short* __restrict__ xb,
    const unsigned short* __restrict__ Wt,
    const float* __restrict__ bq, const float* __restrict__ bk,
    const float* __restrict__ bv, const float* __restrict__ bf,
    float* __restrict__ qf, unsigned short* __restrict__ kv,
    unsigned short* __restrict__ ffnb, int M)
{
    __shared__ unsigned short As[128][40];
    __shared__ unsigned short Bs[128][40];
    const int tid  = threadIdx.x;
    const int lane = tid & 63;
    const int wave = tid >> 6;
    const int wr = wave >> 1, wc = wave & 1;
    const int quad = lane >> 4, m16 = lane & 15;
    const int row0 = blockIdx.x * 128;
    const int col0 = blockIdx.y * 128;

    f32x4 acc[4][4];
    #pragma unroll
    for (int i = 0; i < 4; ++i)
        #pragma unroll
        for (int j = 0; j < 4; ++j) acc[i][j] = 0.f;

    const int lr  = tid >> 1;
    const int lkh = (tid & 1) * 16;

    for (int kt = 0; kt < 256; kt += 32) {
        uint4 a0 = {0,0,0,0}, a1 = {0,0,0,0};
        const int grow = row0 + lr;
        if (grow < M) {
            const uint4* p = (const uint4*)(xb + (size_t)grow * 256 + kt + lkh);
            a0 = p[0]; a1 = p[1];
        }
        *(uint4*)&As[lr][lkh]     = a0;
        *(uint4*)&As[lr][lkh + 8] = a1;
        const uint4* wp = (const uint4*)(Wt + (size_t)(col0 + lr) * 256 + kt + lkh);
        *(uint4*)&Bs[lr][lkh]     = wp[0];
        *(uint4*)&Bs[lr][lkh + 8] = wp[1];
        __syncthreads();
        bf16x8 af[4], bfr[4];
        #pragma unroll
        for (int t = 0; t < 4; ++t) af[t]  = *(const bf16x8*)&As[wr * 64 + t * 16 + m16][quad * 8];
        #pragma unroll
        for (int t = 0; t < 4; ++t) bfr[t] = *(const bf16x8*)&Bs[wc * 64 + t * 16 + m16][quad * 8];
        #pragma unroll
        for (int i = 0; i < 4; ++i)
            #pragma unroll
            for (int j = 0; j < 4; ++j)
                acc[i][j] = __builtin_amdgcn_mfma_f32_16x16x32_bf16(af[i], bfr[j], acc[i][j], 0, 0, 0);
        __syncthreads();
    }

    const int y = blockIdx.y;
    const float* bias = (y == 0) ? bq : (y == 1) ? bk : (y == 2) ? bv : bf;

    if (y == 0) {
        #pragma unroll
        for (int i = 0; i < 4; ++i)
            #pragma unroll
            for (int j = 0; j < 4; ++j) {
                const int col = wc * 64 + j * 16 + m16;
                const float b = bias[col];
                #pragma unroll
                for (int r = 0; r < 4; ++r) {
                    const int row = row0 + wr * 64 + i * 16 + quad * 4 + r;
                    if (row < M) qf[(size_t)row * 128 + col] = acc[i][j][r] + b;
                }
            }
    } else {
        unsigned short* obase = (y == 3) ? ffnb : kv;
        const int ostride = (y == 3) ? 128 : 256;
        const int ocol    = (y == 2) ? 128 : 0;
        #pragma unroll
        for (int i = 0; i < 4; ++i)
            #pragma unroll
            for (int j = 0; j < 4; ++j) {
                const int col = wc * 64 + j * 16 + m16;
                const float b = bias[col];
                #pragma unroll
                for (int r = 0; r < 4; ++r) {
                    const int row = row0 + wr * 64 + i * 16 + quad * 4 + r;
                    if (row < M) obase[(size_t)row * ostride + ocol + col] = f2bf(acc[i][j][r] + b);
                }
            }
    }
}

// ---------------------------------------------------------------------------
// Pass 1: bin edges into NB buckets of 256 nodes. Stage record:
// x = f32 feat bits, y = (src << 8) | (nid & 255).
// ---------------------------------------------------------------------------
__global__ __launch_bounds__(256) void binpass_k(
    const int* __restrict__ dst0, const int* __restrict__ dst1,
    const int* __restrict__ src0, const int* __restrict__ src1,
    const float* __restrict__ feat0, const float* __restrict__ feat1,
    int* __restrict__ cursor, uint2* __restrict__ stage)
{
    __shared__ int hcnt[NB], blkbase[NB], lcur[NB];
    const int tid = threadIdx.x;
    const long base = (long)blockIdx.x * 8192;

    for (int i = tid; i < NB; i += 256) { hcnt[i] = 0; lcur[i] = 0; }
    __syncthreads();

    for (int i = tid; i < 8192; i += 256) {
        const long e = base + i;
        if (e < 2L * EE) {
            const int nid = (e < EE) ? dst0[e] : NN + dst1[e - EE];
            atomicAdd(&hcnt[nid >> 8], 1);
        }
    }
    __syncthreads();
    for (int i = tid; i < NB; i += 256)
        if (hcnt[i]) blkbase[i] = atomicAdd(&cursor[i], hcnt[i]);
    __syncthreads();

    for (int i = tid; i < 8192; i += 256) {
        const long e = base + i;
        if (e < 2L * EE) {
            const bool a = (e < EE);
            const int ee = a ? (int)e : (int)(e - EE);
            const int nid = a ? dst0[ee] : NN + dst1[ee];
            const int s = a ? src0[ee] : src1[ee];
            const float f = a ? feat0[(size_t)ee * 2] : feat1[(size_t)ee * 2];
            const int bk = nid >> 8;
            const int r = atomicAdd(&lcur[bk], 1);
            uint2 rec;
            rec.x = __float_as_uint(f);
            rec.y = ((unsigned int)s << 8) | (unsigned int)(nid & 255);
            stage[(size_t)bk * CAP + blkbase[bk] + r] = rec;
        }
    }
}

__global__ __launch_bounds__(512) void bscan_k(const int* __restrict__ cursor, int* __restrict__ bbase)
{
    __shared__ int part[512];
    const int t = threadIdx.x;
    const int v = (t < NB) ? cursor[t] : 0;
    part[t] = v;
    __syncthreads();
    for (int st = 1; st < 512; st <<= 1) {
        int u = (t >= st) ? part[t - st] : 0;
        __syncthreads();
        part[t] += u;
        __syncthreads();
    }
    if (t < NB) bbase[t] = part[t] - v;
}

// ---------------------------------------------------------------------------
// Pass 2: one block per bucket. Sort bucket records into node order; emit
// erec = {src, f32 feat} plus off/deg per node.
// ---------------------------------------------------------------------------
__global__ __launch_bounds__(256) void sortpass_k(
    const uint2* __restrict__ stage, const int* __restrict__ cursor,
    const int* __restrict__ bbase, uint2* __restrict__ erec,
    int* __restrict__ off, int* __restrict__ deg)
{
    __shared__ int h[256], eb[256], cur[256];
    const int b = blockIdx.x;
    const int t = threadIdx.x;
    const int cntb = cursor[b];
    const int obase = bbase[b];
    const uint2* sb = stage + (size_t)b * CAP;

    h[t] = 0; cur[t] = 0;
    __syncthreads();
    for (int i = t; i < cntb; i += 256) atomicAdd(&h[(int)(sb[i].y & 255u)], 1);
    __syncthreads();
    eb[t] = h[t];
    __syncthreads();
    for (int st = 1; st < 256; st <<= 1) {
        int u = (t >= st) ? eb[t - st] : 0;
        __syncthreads();
        eb[t] += u;
        __syncthreads();
    }
    const int incl = eb[t];
    __syncthreads();
    eb[t] = incl - h[t];          // exclusive
    __syncthreads();

    const int nid = b * 256 + t;
    if (nid < NTOT) {
        off[nid] = obase + eb[t];
        deg[nid] = h[t];
    }

    for (int i = t; i < cntb; i += 256) {
        const uint2 r = sb[i];
        const int loc = (int)(r.y & 255u);
        const int rk = atomicAdd(&cur[loc], 1);
        uint2 o;
        o.x = r.y >> 8;    // src
        o.y = r.x;         // f32 feat bits
        erec[obase + eb[loc] + rk] = o;
    }
}

// ---------------------------------------------------------------------------
// Aggregation, both edge sets in one dispatch: one wave per combined node id.
// q fp32, k/v bf16 (one 512 B contiguous gather per edge), feat fp32.
// ---------------------------------------------------------------------------
__global__ __launch_bounds__(256) void aggregate_k(
    const float* __restrict__ qf, const unsigned short* __restrict__ kv,
    const uint2* __restrict__ erec,
    const int* __restrict__ off, const int* __restrict__ deg,
    unsigned short* __restrict__ att)
{
    const int nid = blockIdx.x * 4 + (threadIdx.x >> 6);
    if (nid >= NTOT) return;
    const int n = (nid >= NN) ? nid - NN : nid;
    const int lane = threadIdx.x & 63;
    const int start = off[nid];
    const int count = deg[nid];

    const float2 q2 = *(const float2*)&qf[(size_t)n * 128 + 2 * lane];
    const float qx = q2.x, qy = q2.y;

    float accx = 0.f, accy = 0.f, z = 0.f;
    const float SCALE = 0.088388347648318447f;  // 1/sqrt(128)

    for (int base = 0; base < count; base += 64) {
        const int m = min(64, count - base);
        const uint2 rr = erec[start + base + min(lane, m - 1)];
        int j = 0;
        for (; j + 3 < m; j += 4) {
            const int s0 = __shfl((int)rr.x, j);
            const int s1 = __shfl((int)rr.x, j + 1);
            const int s2 = __shfl((int)rr.x, j + 2);
            const int s3 = __shfl((int)rr.x, j + 3);
            const float f0 = __int_as_float(__shfl((int)rr.y, j));
            const float f1 = __int_as_float(__shfl((int)rr.y, j + 1));
            const float f2 = __int_as_float(__shfl((int)rr.y, j + 2));
            const float f3 = __int_as_float(__shfl((int)rr.y, j + 3));
            const unsigned int ku0 = *(const unsigned int*)(kv + (size_t)s0 * 256 + 2 * lane);
            const unsigned int vu0 = *(const unsigned int*)(kv + (size_t)s0 * 256 + 128 + 2 * lane);
            const unsigned int ku1 = *(const unsigned int*)(kv + (size_t)s1 * 256 + 2 * lane);
            const unsigned int vu1 = *(const unsigned int*)(kv + (size_t)s1 * 256 + 128 + 2 * lane);
            const unsigned int ku2 = *(const unsigned int*)(kv + (size_t)s2 * 256 + 2 * lane);
            const unsigned int vu2 = *(const unsigned int*)(kv + (size_t)s2 * 256 + 128 + 2 * lane);
            const unsigned int ku3 = *(const unsigned int*)(kv + (size_t)s3 * 256 + 2 * lane);
            const unsigned int vu3 = *(const unsigned int*)(kv + (size_t)s3 * 256 + 128 + 2 * lane);

            float p0 = fmaf(bfhi(ku0), qy, bflo(ku0) * qx);
            float p1 = fmaf(bfhi(ku1), qy, bflo(ku1) * qx);
            float p2 = fmaf(bfhi(ku2), qy, bflo(ku2) * qx);
            float p3 = fmaf(bfhi(ku3), qy, bflo(ku3) * qx);
            #pragma unroll
            for (int mm = 8; mm >= 1; mm >>= 1) {
                p0 += __shfl_xor(p0, mm, 16);
                p1 += __shfl_xor(p1, mm, 16);
                p2 += __shfl_xor(p2, mm, 16);
                p3 += __shfl_xor(p3, mm, 16);
            }
            float sc0 = __expf(fminf(5.f, fmaxf(-5.f, p0 * f0 * SCALE)));
            float sc1 = __expf(fminf(5.f, fmaxf(-5.f, p1 * f1 * SCALE)));
            float sc2 = __expf(fminf(5.f, fmaxf(-5.f, p2 * f2 * SCALE)));
            float sc3 = __expf(fminf(5.f, fmaxf(-5.f, p3 * f3 * SCALE)));
            accx = fmaf(bflo(vu0), sc0, accx); accy = fmaf(bfhi(vu0), sc0, accy); z += sc0;
            accx = fmaf(bflo(vu1), sc1, accx); accy = fmaf(bfhi(vu1), sc1, accy); z += sc1;
            accx = fmaf(bflo(vu2), sc2, accx); accy = fmaf(bfhi(vu2), sc2, accy); z += sc2;
            accx = fmaf(bflo(vu3), sc3, accx); accy = fmaf(bfhi(vu3), sc3, accy); z += sc3;
        }
        for (; j < m; ++j) {
            const int s0 = __shfl((int)rr.x, j);
            const float f0 = __int_as_float(__shfl((int)rr.y, j));
            const unsigned int ku0 = *(const unsigned int*)(kv + (size_t)s0 * 256 + 2 * lane);
            const unsigned int vu0 = *(const unsigned int*)(kv + (size_t)s0 * 256 + 128 + 2 * lane);
            float p0 = fmaf(bfhi(ku0), qy, bflo(ku0) * qx);
            #pragma unroll
            for (int mm = 8; mm >= 1; mm >>= 1) p0 += __shfl_xor(p0, mm, 16);
            float sc0 = __expf(fminf(5.f, fmaxf(-5.f, p0 * f0 * SCALE)));
            accx = fmaf(bflo(vu0), sc0, accx); accy = fmaf(bfhi(vu0), sc0, accy); z += sc0;
        }
    }
    const float inv = 1.f / (z + 1.f);
    const unsigned int o = ((unsigned int)f2bf(accy * inv) << 16) | (unsigned int)f2bf(accx * inv);
    *(unsigned int*)(att + (size_t)nid * 128 + 2 * lane) = o;
}

// ---------------------------------------------------------------------------
// Output GEMM for both sets (blockIdx.y). LN epilogue fully in fp32 registers:
// row sums via shfl over the m16 group + cross-wave LDS combine. No bf16
// round-trip of ah.
// ---------------------------------------------------------------------------
__global__ __launch_bounds__(256) void attn_out_mfma_k(
    const unsigned short* __restrict__ attAll, const unsigned short* __restrict__ Wt,
    const float* __restrict__ bo, const unsigned short* __restrict__ ffnb,
    const float* __restrict__ g, const float* __restrict__ bln,
    float* __restrict__ Yall, int M)
{
    __shared__ unsigned short As[128][40];
    __shared__ unsigned short Bs[128][40];
    __shared__ float rsum[2][128], rsq[2][128];
    __shared__ float meanar[128], invar[128];

    const unsigned short* att = attAll + (size_t)blockIdx.y * NN * 128;
    float* Y = Yall + (size_t)blockIdx.y * NN * 128;

    const int tid  = threadIdx.x;
    const int lane = tid & 63;
    const int wave = tid >> 6;
    const int wr = wave >> 1, wc = wave & 1;
    const int quad = lane >> 4, m16 = lane & 15;
    const int row0 = blockIdx.x * 128;

    f32x4 acc[4][4];
    #pragma unroll
    for (int i = 0; i < 4; ++i)
        #pragma unroll
        for (int j = 0; j < 4; ++j) acc[i][j] = 0.f;

    const int lr  = tid >> 1;
    const int lkh = (tid & 1) * 16;

    for (int kt = 0; kt < 128; kt += 32) {
        uint4 a0 = {0,0,0,0}, a1 = {0,0,0,0};
        const int grow = row0 + lr;
        if (grow < M) {
            const uint4* p = (const uint4*)(att + (size_t)grow * 128 + kt + lkh);
            a0 = p[0]; a1 = p[1];
        }
        *(uint4*)&As[lr][lkh]     = a0;
        *(uint4*)&As[lr][lkh + 8] = a1;
        const uint4* wp = (const uint4*)(Wt + (size_t)lr * 128 + kt + lkh);
        *(uint4*)&Bs[lr][lkh]     = wp[0];
        *(uint4*)&Bs[lr][lkh + 8] = wp[1];
        __syncthreads();
        bf16x8 af[4], bfr[4];
        #pragma unroll
        for (int t = 0; t < 4; ++t) af[t]  = *(const bf16x8*)&As[wr * 64 + t * 16 + m16][quad * 8];
        #pragma unroll
        for (int t = 0; t < 4; ++t) bfr[t] = *(const bf16x8*)&Bs[wc * 64 + t * 16 + m16][quad * 8];
        #pragma unroll
        for (int i = 0; i < 4; ++i)
            #pragma unroll
            for (int j = 0; j < 4; ++j)
                acc[i][j] = __builtin_amdgcn_mfma_f32_16x16x32_bf16(af[i], bfr[j], acc[i][j], 0, 0, 0);
        __syncthreads();
    }

    // ah = C + bo + ffn (fp32 in regs); per-row partial sums
    #pragma unroll
    for (int i = 0; i < 4; ++i) {
        #pragma unroll
        for (int r = 0; r < 4; ++r) {
            const int rl = wr * 64 + i * 16 + quad * 4 + r;
            const int grow = row0 + rl;
            float s = 0.f, q = 0.f;
            #pragma unroll
            for (int j = 0; j < 4; ++j) {
                const int col = wc * 64 + j * 16 + m16;
                float v = acc[i][j][r] + bo[col];
                if (grow < M) v += bflo(ffnb[(size_t)grow * 128 + col]);
                acc[i][j][r] = v;
                s += v; q += v * v;
            }
            #pragma unroll
            for (int mm = 1; mm <= 8; mm <<= 1) {
                s += __shfl_xor(s, mm, 16);
                q += __shfl_xor(q, mm, 16);
            }
            if (m16 == 0) { rsum[wc][rl] = s; rsq[wc][rl] = q; }
        }
    }
    __syncthreads();
    if (tid < 128) {
        const float s = rsum[0][tid] + rsum[1][tid];
        const float q = rsq[0][tid] + rsq[1][tid];
        const float mean = s * (1.f / 128.f);
        const float var  = q * (1.f / 128.f) - mean * mean;
        meanar[tid] = mean;
        invar[tid]  = rsqrtf(fmaxf(var, 0.f) + 1e-5f);
    }
    __syncthreads();

    #pragma unroll
    for (int i = 0; i < 4; ++i) {
        #pragma unroll
        for (int j = 0; j < 4; ++j) {
            const int col = wc * 64 + j * 16 + m16;
            const float gv = g[col], lv = bln[col];
            #pragma unroll
            for (int r = 0; r < 4; ++r) {
                const int rl = wr * 64 + i * 16 + quad * 4 + r;
                const int grow = row0 + rl;
                if (grow < M) {
                    const float v = acc[i][j][r];
                    Y[(size_t)grow * 128 + col] = v + (v - meanar[rl]) * invar[rl] * gv + lv;
                }
            }
        }
    }
}

// ---------------------------------------------------------------------------
extern "C" void kernel_launch(void* const* d_in, const int* in_sizes, int n_in,
                              void* d_out, int out_size, void* d_ws, size_t ws_size,
                              hipStream_t stream) {
    const float* x99   = (const float*)d_in[2];
    const float* feat0 = (const float*)d_in[3];
    const float* feat1 = (const float*)d_in[4];
    const float* Waq   = (const float*)d_in[10];
    const float* Wak   = (const float*)d_in[11];
    const float* Wav   = (const float*)d_in[12];
    const float* Wao   = (const float*)d_in[13];
    const float* Waffn = (const float*)d_in[14];
    const float* baq   = (const float*)d_in[20];
    const float* bak   = (const float*)d_in[21];
    const float* bav   = (const float*)d_in[22];
    const float* bao   = (const float*)d_in[23];
    const float* baffn = (const float*)d_in[24];
    const float* aln_b = (const float*)d_in[26];
    const float* aln_g = (const float*)d_in[28];
    const int* src0 = (const int*)d_in[29];
    const int* dst0 = (const int*)d_in[30];
    const int* src1 = (const int*)d_in[31];
    const int* dst1 = (const int*)d_in[32];

    // workspace (~116 MB)
    unsigned short* xb   = (unsigned short*)d_ws;                 // NN*256 us
    float*          qf   = (float*)(xb + (size_t)NN * 256);       // NN*128 f32
    unsigned short* kv   = (unsigned short*)(qf + (size_t)NN * 128);  // NN*256 us
    unsigned short* ffnb = kv   + (size_t)NN * 256;               // NN*128 us
    unsigned short* att  = ffnb + (size_t)NN * 128;               // 2*NN*128 us
    unsigned short* Wt   = att  + (size_t)NTOT * 128;             // 512*256 us
    unsigned short* Waot = Wt   + (size_t)512 * 256;              // 128*128 us
    int* cursor = (int*)(Waot + 128 * 128);                       // NB
    int* bbase  = cursor + NB;                                    // NB
    int* off    = bbase + NB;                                     // NTOT
    int* deg    = off + NTOT;                                     // NTOT

    float* out = (float*)d_out;
    // stage (16.0 MB) + erec (12.8 MB) parked in d_out; both are fully
    // consumed (sortpass, aggregate) before attn_out writes d_out.
    uint2* stage = (uint2*)d_out;                                 // NB*CAP
    uint2* erec  = stage + (size_t)NB * CAP;                      // 2*EE

    cvt_x_k<<<(NN * AIN / 4 + 255) / 256, 256, 0, stream>>>(x99, xb);
    cvt_w_k<<<640, 256, 0, stream>>>(Waq, Wak, Wav, Waffn, Wao, Wt, Waot);

    const int mtiles = (NN + 127) / 128;   // 391
    qkvf_mfma_k<<<dim3(mtiles, 4), 256, 0, stream>>>(xb, Wt, baq, bak, bav, baffn, qf, kv, ffnb, NN);

    hipMemsetAsync(cursor, 0, NB * sizeof(int), stream);
    binpass_k<<<(2 * EE + 8191) / 8192, 256, 0, stream>>>(
        dst0, dst1, src0, src1, feat0, feat1, cursor, stage);
    bscan_k<<<1, 512, 0, stream>>>(cursor, bbase);
    sortpass_k<<<NB, 256, 0, stream>>>(stage, cursor, bbase, erec, off, deg);

    aggregate_k<<<(NTOT + 3) / 4, 256, 0, stream>>>(qf, kv, erec, off, deg, att);
    attn_out_mfma_k<<<dim3(mtiles, 2), 256, 0, stream>>>(att, Waot, bao, ffnb, aln_g, aln_b, out, NN);
}

// Round 8
// 474.561 us; speedup vs baseline: 2.7103x; 1.0081x over previous
//
#include <hip/hip_runtime.h>
#include <math.h>

#define NN 50000
#define EE 800000
#define AIN 256
#define OH 128

#define NTOT  (2 * NN)        // combined node ids: set0 = [0,NN), set1 = [NN,2NN)
#define NB    391             // buckets of 256 nodes
#define CAP   5120            // per-bucket stage capacity (mean 4092, +16 sigma)

typedef __attribute__((ext_vector_type(8))) short bf16x8;
typedef __attribute__((ext_vector_type(4))) float f32x4;

static __device__ __forceinline__ unsigned short f2bf(float f) {
    union { float f; unsigned int u; } v; v.f = f;
    return (unsigned short)((v.u + 0x7FFFu + ((v.u >> 16) & 1u)) >> 16);
}
static __device__ __forceinline__ float bflo(unsigned int u) { return __uint_as_float(u << 16); }
static __device__ __forceinline__ float bfhi(unsigned int u) { return __uint_as_float(u & 0xFFFF0000u); }

// Fold two per-lane partial registers (edges a, b) over lane-bit `mask`:
// result in lane l holds edge (bit set ? b : a) folded over lanes l, l^mask.
static __device__ __forceinline__ float foldpair(float a, float b, int mask, int lane) {
    const bool hi = (lane & mask) != 0;
    const float keep = hi ? b : a;
    const float send = hi ? a : b;
    return keep + __shfl_xor(send, mask);
}

// ---------------------------------------------------------------------------
__global__ __launch_bounds__(256) void cvt_x_k(const float* __restrict__ x, unsigned short* __restrict__ xb)
{
    const int i = blockIdx.x * 256 + threadIdx.x;
    if (i >= NN * AIN / 4) return;
    const float4 v = ((const float4*)x)[i];
    ushort4 o;
    o.x = f2bf(v.x); o.y = f2bf(v.y); o.z = f2bf(v.z); o.w = f2bf(v.w);
    ((ushort4*)xb)[i] = o;
}

__global__ __launch_bounds__(256) void cvt_w_k(
    const float* __restrict__ Wq, const float* __restrict__ Wk,
    const float* __restrict__ Wv, const float* __restrict__ Wf,
    const float* __restrict__ Wo, unsigned short* __restrict__ Wt,
    unsigned short* __restrict__ Waot)
{
    const int n = blockIdx.x;
    const int k = threadIdx.x;
    if (n < 512) {
        const float* W = (n < 128) ? Wq : (n < 256) ? Wk : (n < 384) ? Wv : Wf;
        Wt[(size_t)n * 256 + k] = f2bf(W[(size_t)k * OH + (n & 127)]);
    } else {
        if (k < 128) Waot[(size_t)(n - 512) * 128 + k] = f2bf(Wo[(size_t)k * OH + (n - 512)]);
    }
}

// ---------------------------------------------------------------------------
// Fused QKV+FFN GEMM, bf16 MFMA 16x16x32. 128x128 tile, BK=32, 4 waves.
// y=0 -> q (fp32 out), y=1 -> k (bf16 into kv col 0), y=2 -> v (bf16 kv col
// 128), y=3 -> ffn (bf16).
// ---------------------------------------------------------------------------
__global__ __launch_bounds__(256) void qkvf_mfma_k(
    const unsigned short* __restrict__ xb,
    const unsigned short* __restrict__ Wt,
    const float* __restrict__ bq, const float* __restrict__ bk,
    const float* __restrict__ bv, const float* __restrict__ bf,
    float* __restrict__ qf, unsigned short* __restrict__ kv,
    unsigned short* __restrict__ ffnb, int M)
{
    __shared__ unsigned short As[128][40];
    __shared__ unsigned short Bs[128][40];
    const int tid  = threadIdx.x;
    const int lane = tid & 63;
    const int wave = tid >> 6;
    const int wr = wave >> 1, wc = wave & 1;
    const int quad = lane >> 4, m16 = lane & 15;
    const int row0 = blockIdx.x * 128;
    const int col0 = blockIdx.y * 128;

    f32x4 acc[4][4];
    #pragma unroll
    for (int i = 0; i < 4; ++i)
        #pragma unroll
        for (int j = 0; j < 4; ++j) acc[i][j] = 0.f;

    const int lr  = tid >> 1;
    const int lkh = (tid & 1) * 16;

    for (int kt = 0; kt < 256; kt += 32) {
        uint4 a0 = {0,0,0,0}, a1 = {0,0,0,0};
        const int grow = row0 + lr;
        if (grow < M) {
            const uint4* p = (const uint4*)(xb + (size_t)grow * 256 + kt + lkh);
            a0 = p[0]; a1 = p[1];
        }
        *(uint4*)&As[lr][lkh]     = a0;
        *(uint4*)&As[lr][lkh + 8] = a1;
        const uint4* wp = (const uint4*)(Wt + (size_t)(col0 + lr) * 256 + kt + lkh);
        *(uint4*)&Bs[lr][lkh]     = wp[0];
        *(uint4*)&Bs[lr][lkh + 8] = wp[1];
        __syncthreads();
        bf16x8 af[4], bfr[4];
        #pragma unroll
        for (int t = 0; t < 4; ++t) af[t]  = *(const bf16x8*)&As[wr * 64 + t * 16 + m16][quad * 8];
        #pragma unroll
        for (int t = 0; t < 4; ++t) bfr[t] = *(const bf16x8*)&Bs[wc * 64 + t * 16 + m16][quad * 8];
        #pragma unroll
        for (int i = 0; i < 4; ++i)
            #pragma unroll
            for (int j = 0; j < 4; ++j)
                acc[i][j] = __builtin_amdgcn_mfma_f32_16x16x32_bf16(af[i], bfr[j], acc[i][j], 0, 0, 0);
        __syncthreads();
    }

    const int y = blockIdx.y;
    const float* bias = (y == 0) ? bq : (y == 1) ? bk : (y == 2) ? bv : bf;

    if (y == 0) {
        #pragma unroll
        for (int i = 0; i < 4; ++i)
            #pragma unroll
            for (int j = 0; j < 4; ++j) {
                const int col = wc * 64 + j * 16 + m16;
                const float b = bias[col];
                #pragma unroll
                for (int r = 0; r < 4; ++r) {
                    const int row = row0 + wr * 64 + i * 16 + quad * 4 + r;
                    if (row < M) qf[(size_t)row * 128 + col] = acc[i][j][r] + b;
                }
            }
    } else {
        unsigned short* obase = (y == 3) ? ffnb : kv;
        const int ostride = (y == 3) ? 128 : 256;
        const int ocol    = (y == 2) ? 128 : 0;
        #pragma unroll
        for (int i = 0; i < 4; ++i)
            #pragma unroll
            for (int j = 0; j < 4; ++j) {
                const int col = wc * 64 + j * 16 + m16;
                const float b = bias[col];
                #pragma unroll
                for (int r = 0; r < 4; ++r) {
                    const int row = row0 + wr * 64 + i * 16 + quad * 4 + r;
                    if (row < M) obase[(size_t)row * ostride + ocol + col] = f2bf(acc[i][j][r] + b);
                }
            }
    }
}

// ---------------------------------------------------------------------------
// Pass 1: bin edges into NB buckets of 256 nodes. Stage record:
// x = f32 feat bits, y = (src << 8) | (nid & 255).
// ---------------------------------------------------------------------------
__global__ __launch_bounds__(256) void binpass_k(
    const int* __restrict__ dst0, const int* __restrict__ dst1,
    const int* __restrict__ src0, const int* __restrict__ src1,
    const float* __restrict__ feat0, const float* __restrict__ feat1,
    int* __restrict__ cursor, uint2* __restrict__ stage)
{
    __shared__ int hcnt[NB], blkbase[NB], lcur[NB];
    const int tid = threadIdx.x;
    const long base = (long)blockIdx.x * 8192;

    for (int i = tid; i < NB; i += 256) { hcnt[i] = 0; lcur[i] = 0; }
    __syncthreads();

    for (int i = tid; i < 8192; i += 256) {
        const long e = base + i;
        if (e < 2L * EE) {
            const int nid = (e < EE) ? dst0[e] : NN + dst1[e - EE];
            atomicAdd(&hcnt[nid >> 8], 1);
        }
    }
    __syncthreads();
    for (int i = tid; i < NB; i += 256)
        if (hcnt[i]) blkbase[i] = atomicAdd(&cursor[i], hcnt[i]);
    __syncthreads();

    for (int i = tid; i < 8192; i += 256) {
        const long e = base + i;
        if (e < 2L * EE) {
            const bool a = (e < EE);
            const int ee = a ? (int)e : (int)(e - EE);
            const int nid = a ? dst0[ee] : NN + dst1[ee];
            const int s = a ? src0[ee] : src1[ee];
            const float f = a ? feat0[(size_t)ee * 2] : feat1[(size_t)ee * 2];
            const int bk = nid >> 8;
            const int r = atomicAdd(&lcur[bk], 1);
            uint2 rec;
            rec.x = __float_as_uint(f);
            rec.y = ((unsigned int)s << 8) | (unsigned int)(nid & 255);
            stage[(size_t)bk * CAP + blkbase[bk] + r] = rec;
        }
    }
}

__global__ __launch_bounds__(512) void bscan_k(const int* __restrict__ cursor, int* __restrict__ bbase)
{
    __shared__ int part[512];
    const int t = threadIdx.x;
    const int v = (t < NB) ? cursor[t] : 0;
    part[t] = v;
    __syncthreads();
    for (int st = 1; st < 512; st <<= 1) {
        int u = (t >= st) ? part[t - st] : 0;
        __syncthreads();
        part[t] += u;
        __syncthreads();
    }
    if (t < NB) bbase[t] = part[t] - v;
}

// ---------------------------------------------------------------------------
// Pass 2: one block per bucket. Sort bucket records into node order; emit
// erec = {src, f32 feat} plus off/deg per node.
// ---------------------------------------------------------------------------
__global__ __launch_bounds__(256) void sortpass_k(
    const uint2* __restrict__ stage, const int* __restrict__ cursor,
    const int* __restrict__ bbase, uint2* __restrict__ erec,
    int* __restrict__ off, int* __restrict__ deg)
{
    __shared__ int h[256], eb[256], cur[256];
    const int b = blockIdx.x;
    const int t = threadIdx.x;
    const int cntb = cursor[b];
    const int obase = bbase[b];
    const uint2* sb = stage + (size_t)b * CAP;

    h[t] = 0; cur[t] = 0;
    __syncthreads();
    for (int i = t; i < cntb; i += 256) atomicAdd(&h[(int)(sb[i].y & 255u)], 1);
    __syncthreads();
    eb[t] = h[t];
    __syncthreads();
    for (int st = 1; st < 256; st <<= 1) {
        int u = (t >= st) ? eb[t - st] : 0;
        __syncthreads();
        eb[t] += u;
        __syncthreads();
    }
    const int incl = eb[t];
    __syncthreads();
    eb[t] = incl - h[t];          // exclusive
    __syncthreads();

    const int nid = b * 256 + t;
    if (nid < NTOT) {
        off[nid] = obase + eb[t];
        deg[nid] = h[t];
    }

    for (int i = t; i < cntb; i += 256) {
        const uint2 r = sb[i];
        const int loc = (int)(r.y & 255u);
        const int rk = atomicAdd(&cur[loc], 1);
        uint2 o;
        o.x = r.y >> 8;    // src
        o.y = r.x;         // f32 feat bits
        erec[obase + eb[loc] + rk] = o;
    }
}

// ---------------------------------------------------------------------------
// Aggregation, both edge sets in one dispatch: one wave per combined node id.
// Batched-8 edge processing: per-lane dot partials folded with a pairwise
// select-shuffle tree (edge lane&7), score math amortized across lanes,
// 16 gather loads in flight per batch. q fp32, k/v bf16, feat fp32.
// ---------------------------------------------------------------------------
__global__ __launch_bounds__(256) void aggregate_k(
    const float* __restrict__ qf, const unsigned short* __restrict__ kv,
    const uint2* __restrict__ erec,
    const int* __restrict__ off, const int* __restrict__ deg,
    unsigned short* __restrict__ att)
{
    const int nid = blockIdx.x * 4 + (threadIdx.x >> 6);
    if (nid >= NTOT) return;
    const int n = (nid >= NN) ? nid - NN : nid;
    const int lane = threadIdx.x & 63;
    const int start = off[nid];
    const int count = deg[nid];

    const float2 q2 = *(const float2*)&qf[(size_t)n * 128 + 2 * lane];
    const float qx = q2.x, qy = q2.y;

    float accx = 0.f, accy = 0.f, zp = 0.f;
    const float SCALE = 0.088388347648318447f;  // 1/sqrt(128)
    const int slot = lane & 7;

    for (int base = 0; base < count; base += 64) {
        const int m = min(64, count - base);
        const uint2 rr = erec[start + base + min(lane, m - 1)];
        for (int j0 = 0; j0 < m; j0 += 8) {
            const int mb = min(8, m - j0);
            unsigned int ku[8], vu[8];
            // 16 gathers in flight; pad slots read clamped (valid) records.
            #pragma unroll
            for (int s = 0; s < 8; ++s) {
                const int src = __shfl((int)rr.x, j0 + s);
                const unsigned short* kp = kv + (size_t)src * 256 + 2 * lane;
                ku[s] = *(const unsigned int*)kp;
                vu[s] = *(const unsigned int*)(kp + 128);
            }
            float p[8];
            #pragma unroll
            for (int s = 0; s < 8; ++s)
                p[s] = fmaf(bfhi(ku[s]), qy, bflo(ku[s]) * qx);
            // fold: edge (lane&7) head-sum in every lane (dup at +8)
            float r01 = foldpair(p[0], p[1], 1, lane);
            float r23 = foldpair(p[2], p[3], 1, lane);
            float r45 = foldpair(p[4], p[5], 1, lane);
            float r67 = foldpair(p[6], p[7], 1, lane);
            float r03 = foldpair(r01, r23, 2, lane);
            float r47 = foldpair(r45, r67, 2, lane);
            float r07 = foldpair(r03, r47, 4, lane);
            r07 += __shfl_xor(r07, 8);
            // score for this lane's slot
            const float f = __int_as_float(__shfl((int)rr.y, j0 + slot));
            float sc = __expf(fminf(5.f, fmaxf(-5.f, r07 * f * SCALE)));
            if (slot >= mb) sc = 0.f;
            zp += sc;
            // v accumulation: broadcast each slot's score within the head group
            #pragma unroll
            for (int s = 0; s < 8; ++s) {
                const float scb = __shfl(sc, (lane & 48) + s);
                accx = fmaf(bflo(vu[s]), scb, accx);
                accy = fmaf(bfhi(vu[s]), scb, accy);
            }
        }
    }
    // combine z over the 8 slots (halves at +8 are duplicates: fold 1,2,4 only)
    float z = zp;
    z += __shfl_xor(z, 1);
    z += __shfl_xor(z, 2);
    z += __shfl_xor(z, 4);

    const float inv = 1.f / (z + 1.f);
    const unsigned int o = ((unsigned int)f2bf(accy * inv) << 16) | (unsigned int)f2bf(accx * inv);
    *(unsigned int*)(att + (size_t)nid * 128 + 2 * lane) = o;
}

// ---------------------------------------------------------------------------
// Output GEMM for both sets (blockIdx.y). LN epilogue fully in fp32 registers.
// ---------------------------------------------------------------------------
__global__ __launch_bounds__(256) void attn_out_mfma_k(
    const unsigned short* __restrict__ attAll, const unsigned short* __restrict__ Wt,
    const float* __restrict__ bo, const unsigned short* __restrict__ ffnb,
    const float* __restrict__ g, const float* __restrict__ bln,
    float* __restrict__ Yall, int M)
{
    __shared__ unsigned short As[128][40];
    __shared__ unsigned short Bs[128][40];
    __shared__ float rsum[2][128], rsq[2][128];
    __shared__ float meanar[128], invar[128];

    const unsigned short* att = attAll + (size_t)blockIdx.y * NN * 128;
    float* Y = Yall + (size_t)blockIdx.y * NN * 128;

    const int tid  = threadIdx.x;
    const int lane = tid & 63;
    const int wave = tid >> 6;
    const int wr = wave >> 1, wc = wave & 1;
    const int quad = lane >> 4, m16 = lane & 15;
    const int row0 = blockIdx.x * 128;

    f32x4 acc[4][4];
    #pragma unroll
    for (int i = 0; i < 4; ++i)
        #pragma unroll
        for (int j = 0; j < 4; ++j) acc[i][j] = 0.f;

    const int lr  = tid >> 1;
    const int lkh = (tid & 1) * 16;

    for (int kt = 0; kt < 128; kt += 32) {
        uint4 a0 = {0,0,0,0}, a1 = {0,0,0,0};
        const int grow = row0 + lr;
        if (grow < M) {
            const uint4* p = (const uint4*)(att + (size_t)grow * 128 + kt + lkh);
            a0 = p[0]; a1 = p[1];
        }
        *(uint4*)&As[lr][lkh]     = a0;
        *(uint4*)&As[lr][lkh + 8] = a1;
        const uint4* wp = (const uint4*)(Wt + (size_t)lr * 128 + kt + lkh);
        *(uint4*)&Bs[lr][lkh]     = wp[0];
        *(uint4*)&Bs[lr][lkh + 8] = wp[1];
        __syncthreads();
        bf16x8 af[4], bfr[4];
        #pragma unroll
        for (int t = 0; t < 4; ++t) af[t]  = *(const bf16x8*)&As[wr * 64 + t * 16 + m16][quad * 8];
        #pragma unroll
        for (int t = 0; t < 4; ++t) bfr[t] = *(const bf16x8*)&Bs[wc * 64 + t * 16 + m16][quad * 8];
        #pragma unroll
        for (int i = 0; i < 4; ++i)
            #pragma unroll
            for (int j = 0; j < 4; ++j)
                acc[i][j] = __builtin_amdgcn_mfma_f32_16x16x32_bf16(af[i], bfr[j], acc[i][j], 0, 0, 0);
        __syncthreads();
    }

    // ah = C + bo + ffn (fp32 in regs); per-row partial sums
    #pragma unroll
    for (int i = 0; i < 4; ++i) {
        #pragma unroll
        for (int r = 0; r < 4; ++r) {
            const int rl = wr * 64 + i * 16 + quad * 4 + r;
            const int grow = row0 + rl;
            float s = 0.f, q = 0.f;
            #pragma unroll
            for (int j = 0; j < 4; ++j) {
                const int col = wc * 64 + j * 16 + m16;
                float v = acc[i][j][r] + bo[col];
                if (grow < M) v += bflo(ffnb[(size_t)grow * 128 + col]);
                acc[i][j][r] = v;
                s += v; q += v * v;
            }
            #pragma unroll
            for (int mm = 1; mm <= 8; mm <<= 1) {
                s += __shfl_xor(s, mm, 16);
                q += __shfl_xor(q, mm, 16);
            }
            if (m16 == 0) { rsum[wc][rl] = s; rsq[wc][rl] = q; }
        }
    }
    __syncthreads();
    if (tid < 128) {
        const float s = rsum[0][tid] + rsum[1][tid];
        const float q = rsq[0][tid] + rsq[1][tid];
        const float mean = s * (1.f / 128.f);
        const float var  = q * (1.f / 128.f) - mean * mean;
        meanar[tid] = mean;
        invar[tid]  = rsqrtf(fmaxf(var, 0.f) + 1e-5f);
    }
    __syncthreads();

    #pragma unroll
    for (int i = 0; i < 4; ++i) {
        #pragma unroll
        for (int j = 0; j < 4; ++j) {
            const int col = wc * 64 + j * 16 + m16;
            const float gv = g[col], lv = bln[col];
            #pragma unroll
            for (int r = 0; r < 4; ++r) {
                const int rl = wr * 64 + i * 16 + quad * 4 + r;
                const int grow = row0 + rl;
                if (grow < M) {
                    const float v = acc[i][j][r];
                    Y[(size_t)grow * 128 + col] = v + (v - meanar[rl]) * invar[rl] * gv + lv;
                }
            }
        }
    }
}

// ---------------------------------------------------------------------------
extern "C" void kernel_launch(void* const* d_in, const int* in_sizes, int n_in,
                              void* d_out, int out_size, void* d_ws, size_t ws_size,
                              hipStream_t stream) {
    const float* x99   = (const float*)d_in[2];
    const float* feat0 = (const float*)d_in[3];
    const float* feat1 = (const float*)d_in[4];
    const float* Waq   = (const float*)d_in[10];
    const float* Wak   = (const float*)d_in[11];
    const float* Wav   = (const float*)d_in[12];
    const float* Wao   = (const float*)d_in[13];
    const float* Waffn = (const float*)d_in[14];
    const float* baq   = (const float*)d_in[20];
    const float* bak   = (const float*)d_in[21];
    const float* bav   = (const float*)d_in[22];
    const float* bao   = (const float*)d_in[23];
    const float* baffn = (const float*)d_in[24];
    const float* aln_b = (const float*)d_in[26];
    const float* aln_g = (const float*)d_in[28];
    const int* src0 = (const int*)d_in[29];
    const int* dst0 = (const int*)d_in[30];
    const int* src1 = (const int*)d_in[31];
    const int* dst1 = (const int*)d_in[32];

    // workspace (~116 MB)
    unsigned short* xb   = (unsigned short*)d_ws;                 // NN*256 us
    float*          qf   = (float*)(xb + (size_t)NN * 256);       // NN*128 f32
    unsigned short* kv   = (unsigned short*)(qf + (size_t)NN * 128);  // NN*256 us
    unsigned short* ffnb = kv   + (size_t)NN * 256;               // NN*128 us
    unsigned short* att  = ffnb + (size_t)NN * 128;               // 2*NN*128 us
    unsigned short* Wt   = att  + (size_t)NTOT * 128;             // 512*256 us
    unsigned short* Waot = Wt   + (size_t)512 * 256;              // 128*128 us
    int* cursor = (int*)(Waot + 128 * 128);                       // NB
    int* bbase  = cursor + NB;                                    // NB
    int* off    = bbase + NB;                                     // NTOT
    int* deg    = off + NTOT;                                     // NTOT

    float* out = (float*)d_out;
    // stage (16.0 MB) + erec (12.8 MB) parked in d_out; both are fully
    // consumed (sortpass, aggregate) before attn_out writes d_out.
    uint2* stage = (uint2*)d_out;                                 // NB*CAP
    uint2* erec  = stage + (size_t)NB * CAP;                      // 2*EE

    cvt_x_k<<<(NN * AIN / 4 + 255) / 256, 256, 0, stream>>>(x99, xb);
    cvt_w_k<<<640, 256, 0, stream>>>(Waq, Wak, Wav, Waffn, Wao, Wt, Waot);

    const int mtiles = (NN + 127) / 128;   // 391
    qkvf_mfma_k<<<dim3(mtiles, 4), 256, 0, stream>>>(xb, Wt, baq, bak, bav, baffn, qf, kv, ffnb, NN);

    hipMemsetAsync(cursor, 0, NB * sizeof(int), stream);
    binpass_k<<<(2 * EE + 8191) / 8192, 256, 0, stream>>>(
        dst0, dst1, src0, src1, feat0, feat1, cursor, stage);
    bscan_k<<<1, 512, 0, stream>>>(cursor, bbase);
    sortpass_k<<<NB, 256, 0, stream>>>(stage, cursor, bbase, erec, off, deg);

    aggregate_k<<<(NTOT + 3) / 4, 256, 0, stream>>>(qf, kv, erec, off, deg, att);
    attn_out_mfma_k<<<dim3(mtiles, 2), 256, 0, stream>>>(att, Waot, bao, ffnb, aln_g, aln_b, out, NN);
}